// Round 14
// baseline (257.544 us; speedup 1.0000x reference)
//
#include <hip/hip_runtime.h>
#include <math.h>

#define NN 4096
#define RB 128  // readout stage-1 blocks

typedef __attribute__((ext_vector_type(8))) short bf16x8;
typedef __attribute__((ext_vector_type(4))) float f32x4;

// ---------- helpers ----------
__device__ __forceinline__ unsigned encf(float f) {
  unsigned u = __float_as_uint(f);
  return (u & 0x80000000u) ? ~u : (u | 0x80000000u);
}
__device__ __forceinline__ float decf(unsigned u) {
  return __uint_as_float((u & 0x80000000u) ? (u ^ 0x80000000u) : ~u);
}
__device__ __forceinline__ unsigned short f2bf(float f) {
  unsigned u = __float_as_uint(f);
  return (unsigned short)((u + 0x7fffu + ((u >> 16) & 1u)) >> 16);
}

// ---------- pos = img @ Wp + bp  (+ init out/dmax/counters in block 0) ----------
__global__ void k_pos(const float* img, const float* Wp, const float* bp, float* pos,
                      float* out, unsigned* dmax, int* cnt) {
  if (blockIdx.x == 0) {
    int tt = threadIdx.x;
    out[tt] = 0.f; out[256 + tt] = 0.f;
    if (tt == 0) *dmax = 0u;
    if (tt < 3) cnt[tt] = 0;
  }
  int t = blockIdx.x * 256 + threadIdx.x;
  if (t >= NN * 12) return;
  int i = t / 12, d = t % 12;
  float s = bp[d];
#pragma unroll
  for (int k = 0; k < 6; ++k) s += img[i * 6 + k] * Wp[k * 12 + d];
  pos[t] = s;
}

// ---------- fused attention + both layernorms + sumsq + bf16 convert ----------
// attn: branch-free softmax (scores tiny: |s|<~0.5, exp safe without max-shift).
// shfl_xor butterfly leaves reductions in ALL lanes -> each wave immediately
// LayerNorms its 2 rows (wave-level reductions, no extra barriers / pos1 buffer).
// Also zeroes degA for this block's rows (consumed by k_d2m<true> atomics).
__global__ __launch_bounds__(256) void k_attnln(const float* pos, const float* feat,
                                                const float* g, const float* b,
                                                const float* pg, const float* pb,
                                                float* x0, unsigned short* x0h,
                                                float* sqv, int* degA) {
  __shared__ float sp[12][256];
  int t = threadIdx.x, lane = t & 63, w = t >> 6;
  int ib = blockIdx.x * 8 + w * 2;  // 2 rows per wave, 8 per block
  if (t < 8) degA[blockIdx.x * 8 + t] = 0;
  float pi[2][12];
#pragma unroll
  for (int r = 0; r < 2; ++r)
#pragma unroll
    for (int d = 0; d < 12; ++d) pi[r][d] = pos[(ib + r) * 12 + d] * 0.28867513459481287f;
  float sl[2] = {0.f, 0.f};
  float acc[2][12] = {};
  const float4* p4 = (const float4*)pos;
  for (int kt = 0; kt < NN; kt += 256) {
    __syncthreads();  // previous tile fully consumed
    int j = kt + t;
    float4 a = p4[j * 3 + 0], bb = p4[j * 3 + 1], c = p4[j * 3 + 2];
    sp[0][t] = a.x; sp[1][t] = a.y; sp[2][t] = a.z; sp[3][t] = a.w;
    sp[4][t] = bb.x; sp[5][t] = bb.y; sp[6][t] = bb.z; sp[7][t] = bb.w;
    sp[8][t] = c.x; sp[9][t] = c.y; sp[10][t] = c.z; sp[11][t] = c.w;
    __syncthreads();
#pragma unroll
    for (int q = 0; q < 4; ++q) {
      int jj = q * 64 + lane;
      float pj[12];
#pragma unroll
      for (int d = 0; d < 12; ++d) pj[d] = sp[d][jj];
#pragma unroll
      for (int r = 0; r < 2; ++r) {
        float s = 0.f;
#pragma unroll
        for (int d = 0; d < 12; ++d) s = fmaf(pi[r][d], pj[d], s);
        float e = __expf(s);
        sl[r] += e;
#pragma unroll
        for (int d = 0; d < 12; ++d) acc[r][d] = fmaf(e, pj[d], acc[r][d]);
      }
    }
  }
#pragma unroll
  for (int r = 0; r < 2; ++r) {
    int row = ib + r;
    float s = sl[r];
#pragma unroll
    for (int o = 32; o > 0; o >>= 1) s += __shfl_xor(s, o);
    float pa[12];
#pragma unroll
    for (int d = 0; d < 12; ++d) {
      float ad = acc[r][d];
#pragma unroll
      for (int o = 32; o > 0; o >>= 1) ad += __shfl_xor(ad, o);
      pa[d] = ad;  // all lanes hold the full reduced value
    }
    float inv = 1.f / s;
#pragma unroll
    for (int d = 0; d < 12; ++d) pa[d] *= inv;  // attended pos row
    // pos layernorm (12-wide, redundant per lane)
    float pm = 0.f;
#pragma unroll
    for (int d = 0; d < 12; ++d) pm += pa[d];
    pm *= (1.f / 12.f);
    float pvar = 0.f;
#pragma unroll
    for (int d = 0; d < 12; ++d) { float dd = pa[d] - pm; pvar += dd * dd; }
    pvar *= (1.f / 12.f);
    float ps = 1.f / sqrtf(pvar + 1e-5f);
    // feature layernorm (500-wide) via wave reduction
    float fv[8], lsum = 0.f;
#pragma unroll
    for (int q = 0; q < 8; ++q) {
      int c = lane + q * 64;
      fv[q] = (c < 500) ? feat[(size_t)row * 500 + c] : 0.f;
      lsum += fv[q];
    }
#pragma unroll
    for (int o = 32; o > 0; o >>= 1) lsum += __shfl_xor(lsum, o);
    float m = lsum * (1.f / 500.f);
    float lvar = 0.f;
#pragma unroll
    for (int q = 0; q < 8; ++q) {
      int c = lane + q * 64;
      if (c < 500) { float dd = fv[q] - m; lvar += dd * dd; }
    }
#pragma unroll
    for (int o = 32; o > 0; o >>= 1) lvar += __shfl_xor(lvar, o);
    float scale = 1.f / sqrtf(lvar * (1.f / 500.f) + 1e-5f);
    float sq = 0.f;
#pragma unroll
    for (int q = 0; q < 8; ++q) {
      int c = lane + q * 64;
      float val;
      if (c < 500) val = (fv[q] - m) * scale * g[c] + b[c];
      else         val = (pa[c - 500] - pm) * ps * pg[c - 500] + pb[c - 500];
      x0[(size_t)row * 512 + c] = val;
      x0h[(size_t)row * 512 + c] = f2bf(val);
      sq += val * val;
    }
#pragma unroll
    for (int o = 32; o > 0; o >>= 1) sq += __shfl_xor(sq, o);
    if (lane == 0) sqv[row] = sq;
  }
}

// ---------- MFMA d2 tiles (128x128, upper tile pairs): max / mask pass ----------
// T4 pipeline (m201 pattern): double-buffered LDS; issue next panel's 8 DMAs, then
// COUNTED s_waitcnt vmcnt(8), sched_barrier(0), raw s_barrier. No vmcnt(0) drain in
// the loop body. Source pre-swizzled (chunk = (lane&7)^(row&7)); reads same XOR.
// Pass A records per-tile min over gi<gj; pass B skips GEMM when tileMin >= thr,
// zeroes mirror tiles (no memset) and atomically accumulates integer deg[j]
// (zero atomics on skip paths; formula consumers use 1/sqrt(1+deg) inline).
#define BK 64
template <bool MASK>
__global__ __launch_bounds__(256) void k_d2m(const unsigned short* X, const float* sqv,
                                             unsigned* dmax, float* tileMin,
                                             unsigned char* ATm, int* deg) {
  __shared__ unsigned short As[2][128 * BK];
  __shared__ unsigned short Bs[2][128 * BK];
  __shared__ float wmax[4], wmin[4];
  const int NT = NN / 128;
  int bid0 = blockIdx.x;
  int bid = (bid0 & 7) * 66 + (bid0 >> 3);  // 528 total, bijective
  int ti = 0, rem = bid;
  while (rem >= NT - ti) { rem -= NT - ti; ++ti; }
  int tj = ti + rem;
  int t = threadIdx.x, lane = t & 63, w = t >> 6;
  int wr = w >> 1, wc = w & 1;  // wave's 64x64 sub-tile
  const unsigned short* Abase = X + (size_t)ti * 128 * 512;
  const unsigned short* Bbase = X + (size_t)tj * 128 * 512;
  int lr = lane >> 3, lc = lane & 7;

  float thr = 0.f;
  if (MASK) {
    thr = 0.5f * decf(*dmax);
    uint4 z = make_uint4(0u, 0u, 0u, 0u);
    if (ti != tj) {  // mirror tile (rows ti, cols tj) never receives mask writes
#pragma unroll
      for (int q0 = 0; q0 < 4; ++q0) {
        int q = t + q0 * 256; int r = q >> 3, c4 = q & 7;
        *(uint4*)(ATm + (size_t)(ti * 128 + r) * NN + tj * 128 + c4 * 16) = z;
      }
    }
    if (tileMin[blockIdx.x] >= thr) {  // no element can pass -> zero tile, skip GEMM
#pragma unroll
      for (int q0 = 0; q0 < 4; ++q0) {
        int q = t + q0 * 256; int r = q >> 3, c4 = q & 7;
        *(uint4*)(ATm + (size_t)(tj * 128 + r) * NN + ti * 128 + c4 * 16) = z;
      }
      return;
    }
  }

  auto stage = [&](int buf, int k0) {  // 8 DMAs per wave (4x A + 4x B)
#pragma unroll
    for (int i = 0; i < 4; ++i) {
      int q = w * 4 + i;
      int r = q * 8 + lr;
      int cs = lc ^ (r & 7);  // pre-swizzled source chunk
      __builtin_amdgcn_global_load_lds(
          (const __attribute__((address_space(1))) unsigned int*)(Abase + (size_t)r * 512 + k0 + cs * 8),
          (__attribute__((address_space(3))) unsigned int*)(&As[buf][q * 512]), 16, 0, 0);
      __builtin_amdgcn_global_load_lds(
          (const __attribute__((address_space(1))) unsigned int*)(Bbase + (size_t)r * 512 + k0 + cs * 8),
          (__attribute__((address_space(3))) unsigned int*)(&Bs[buf][q * 512]), 16, 0, 0);
    }
  };

  stage(0, 0);  // 8 outstanding

  f32x4 acc[4][4] = {};
  int rl = lane & 15, kg = lane >> 4;
  for (int step = 0; step < 8; ++step) {
    int cur = step & 1;
    if (step < 7) {
      stage(cur ^ 1, (step + 1) * BK);  // +8 in flight (16 total)
      asm volatile("s_waitcnt vmcnt(8)" ::: "memory");  // cur's 8 retired (in-order)
    } else {
      asm volatile("s_waitcnt vmcnt(0)" ::: "memory");
    }
    __builtin_amdgcn_sched_barrier(0);
    __builtin_amdgcn_s_barrier();  // all waves' cur panel visible
#pragma unroll
    for (int ks = 0; ks < 2; ++ks) {
      bf16x8 af[4], bq[4];
#pragma unroll
      for (int f = 0; f < 4; ++f) {
        int rA = wr * 64 + f * 16 + rl;
        af[f] = *(const bf16x8*)(&As[cur][rA * BK + (((ks * 4 + kg) ^ (rA & 7)) << 3)]);
        int rB = wc * 64 + f * 16 + rl;
        bq[f] = *(const bf16x8*)(&Bs[cur][rB * BK + (((ks * 4 + kg) ^ (rB & 7)) << 3)]);
      }
#pragma unroll
      for (int a = 0; a < 4; ++a)
#pragma unroll
        for (int b = 0; b < 4; ++b)
          acc[a][b] = __builtin_amdgcn_mfma_f32_16x16x32_bf16(af[a], bq[b], acc[a][b], 0, 0, 0);
    }
    __builtin_amdgcn_sched_barrier(0);  // pin ds_reads before the reuse barrier
    __builtin_amdgcn_s_barrier();       // all reads of cur done before its overwrite
  }
  // C/D layout: col = lane&15, row = (lane>>4)*4 + reg   [m89/m91 verified]
  int rbase = ti * 128 + wr * 64 + ((lane >> 4) << 2);
  int cbase = tj * 128 + wc * 64 + (lane & 15);
  if (!MASK) {
    float lm = -1e30f, lmin = 1e30f;
#pragma unroll
    for (int a = 0; a < 4; ++a) {
      float si[4];
#pragma unroll
      for (int r = 0; r < 4; ++r) si[r] = sqv[rbase + a * 16 + r];
#pragma unroll
      for (int b = 0; b < 4; ++b) {
        int gj = cbase + b * 16;
        float sj = sqv[gj];
#pragma unroll
        for (int r = 0; r < 4; ++r) {
          float d2v = si[r] - 2.f * acc[a][b][r] + sj;
          lm = fmaxf(lm, d2v);
          if (rbase + a * 16 + r < gj) lmin = fminf(lmin, d2v);
        }
      }
    }
#pragma unroll
    for (int o = 32; o > 0; o >>= 1) {
      lm = fmaxf(lm, __shfl_xor(lm, o));
      lmin = fminf(lmin, __shfl_xor(lmin, o));
    }
    if (lane == 0) { wmax[w] = lm; wmin[w] = lmin; }
    __syncthreads();
    if (t == 0) {
      atomicMax(dmax, encf(fmaxf(fmaxf(wmax[0], wmax[1]), fmaxf(wmax[2], wmax[3]))));
      tileMin[blockIdx.x] = fminf(fminf(wmin[0], wmin[1]), fminf(wmin[2], wmin[3]));
    }
  } else {
#pragma unroll
    for (int b = 0; b < 4; ++b) {
      int gj = cbase + b * 16;
      float sj = sqv[gj];
      int rowcnt = 0;
#pragma unroll
      for (int a = 0; a < 4; ++a) {
        int gi0 = rbase + a * 16;
        union { unsigned char c[4]; unsigned u; } m4;
#pragma unroll
        for (int r = 0; r < 4; ++r) {
          float d2v = sqv[gi0 + r] - 2.f * acc[a][b][r] + sj;
          unsigned char mv = (d2v < thr && (gi0 + r) < gj) ? 1 : 0;
          m4.c[r] = mv; rowcnt += mv;
        }
        *(unsigned*)(ATm + (size_t)gj * NN + gi0) = m4.u;  // AT[j][i..i+3]
      }
      if (rowcnt) atomicAdd(&deg[gj], rowcnt);
    }
  }
}

// ---------- fp32 GEMM + row scale: C[i][c] = (A@B)[i][c] / sqrt(1+deg[i]) ----------
__global__ __launch_bounds__(256) void k_gemm(const float* A, const float* B, const int* deg,
                                              float* C, int M, int N, int K) {
  __shared__ float As[32][17];
  __shared__ float Bs[16][64];
  int t = threadIdx.x, tx = t & 15, ty = t >> 4;
  int nbx = N >> 6;
  int total = gridDim.x;
  int bid0 = blockIdx.x;
  int bid = (bid0 & 7) * (total >> 3) + (bid0 >> 3);  // bijective: total%8==0
  int m0 = (bid / nbx) * 32, n0 = (bid % nbx) * 64;
  int ar = t >> 3, ac = (t * 2) & 15;   // A stage: 2 floats/thread
  int br = t >> 4, bc = (t & 15) * 4;   // B stage: 4 floats/thread
  float2 ra = *(const float2*)(A + (size_t)(m0 + ar) * K + ac);
  float4 rb = *(const float4*)(B + (size_t)br * N + n0 + bc);
  float acc[2][4] = {};
  for (int k0 = 0; k0 < K; k0 += 16) {
    As[ar][ac] = ra.x; As[ar][ac + 1] = ra.y;
    *(float4*)(&Bs[br][bc]) = rb;
    __syncthreads();
    if (k0 + 16 < K) {  // prefetch next panel (overlaps compute)
      ra = *(const float2*)(A + (size_t)(m0 + ar) * K + k0 + 16 + ac);
      rb = *(const float4*)(B + (size_t)(k0 + 16 + br) * N + n0 + bc);
    }
#pragma unroll
    for (int kk = 0; kk < 16; ++kk) {
      float av[2], bv[4];
#pragma unroll
      for (int u = 0; u < 2; ++u) av[u] = As[ty * 2 + u][kk];
#pragma unroll
      for (int u = 0; u < 4; ++u) bv[u] = Bs[kk][tx * 4 + u];
#pragma unroll
      for (int a = 0; a < 2; ++a)
#pragma unroll
        for (int b2 = 0; b2 < 4; ++b2) acc[a][b2] = fmaf(av[a], bv[b2], acc[a][b2]);
    }
    __syncthreads();
  }
#pragma unroll
  for (int a = 0; a < 2; ++a) {
    float dv = 1.f / sqrtf((float)(1 + deg[m0 + ty * 2 + a]));
#pragma unroll
    for (int b2 = 0; b2 < 4; ++b2)
      C[(size_t)(m0 + ty * 2 + a) * N + n0 + tx * 4 + b2] = acc[a][b2] * dv;
  }
}

// ---------- fused: xg row + relu + y2[j] = dinv[j]*dot(xg[j], Wpool) ----------
// Fast path: deg[j]==0 -> no neighbors, skip the mask scan (exact).
__global__ __launch_bounds__(256) void k_agg(const float* y, const unsigned char* ATm,
                                             const int* deg, const float* bias,
                                             const float* Wpool, float* out, float* y2, int n) {
  __shared__ unsigned char mrow[256];
  __shared__ int s_any;
  __shared__ float red[256];
  int j = blockIdx.x, t = threadIdx.x;
  int dg = deg[j];
  float dj = 1.f / sqrtf((float)(1 + dg));
  float acc = y[(size_t)j * 256 + t];
  if (dg != 0) {
    for (int i0 = 0; i0 < n; i0 += 256) {
      if (t == 0) s_any = 0;
      __syncthreads();
      unsigned char m = ATm[(size_t)j * n + i0 + t];
      mrow[t] = m;
      if (m) s_any = 1;
      __syncthreads();
      if (s_any) {
        for (int u = 0; u < 256; ++u)
          if (mrow[u]) acc += y[(size_t)(i0 + u) * 256 + t];
      }
      __syncthreads();
    }
  }
  float o = fmaxf(dj * acc + bias[t], 0.f);
  out[(size_t)j * 256 + t] = o;
  red[t] = o * Wpool[t]; __syncthreads();
  for (int s = 128; s > 0; s >>= 1) { if (t < s) red[t] += red[t + s]; __syncthreads(); }
  if (t == 0) y2[j] = dj * red[0];
}

// ---------- score[j] = tanh(dinv[j]*(y2[j] + sum_{i:AT[j,i]} y2[i]) + bpool) ----------
__global__ __launch_bounds__(256) void k_scorek(const float* y2, const unsigned char* ATm,
                                                const int* deg, const float* bp,
                                                float* score, int n) {
  int w = threadIdx.x >> 6, lane = threadIdx.x & 63;
  int j = blockIdx.x * 4 + w;
  if (j >= n) return;
  int dg = deg[j];
  float dj = 1.f / sqrtf((float)(1 + dg));
  float s = 0.f;
  if (dg != 0) {  // deg>0: scan the row
    const uint4* row = (const uint4*)(ATm + (size_t)j * n);
    for (int p = lane; p < n / 16; p += 64) {
      uint4 v = row[p];
      if (v.x | v.y | v.z | v.w) {
        int base = p * 16;
#pragma unroll
        for (int q = 0; q < 4; ++q) {
          unsigned u = (&v.x)[q];
#pragma unroll
          for (int b2 = 0; b2 < 4; ++b2)
            if ((u >> (8 * b2)) & 0xffu) s += y2[base + q * 4 + b2];
        }
      }
    }
    for (int sh = 32; sh > 0; sh >>= 1) s += __shfl_down(s, sh);
  }
  if (lane == 0) score[j] = tanhf(dj * (y2[j] + s) + bp[0]);
}

// ---------- radix-select top-k (exact PyG set semantics; output in index order) ----------
__global__ __launch_bounds__(1024) void k_topsel(const float* score, int n, int k,
                                                 int* perm, float* vals) {
  __shared__ unsigned keys[4096];
  __shared__ unsigned hist[256];
  __shared__ unsigned s_state[2];  // [0]=prefix(cutoff), [1]=need(ties to take)
  __shared__ unsigned woff[16];
  int t = threadIdx.x, lane = t & 63, w = t >> 6;
  for (int i = t; i < 4096; i += 1024) keys[i] = (i < n) ? encf(score[i]) : 0u;
  if (t == 0) { s_state[0] = 0u; s_state[1] = (unsigned)k; }
  __syncthreads();

  for (int pass = 0; pass < 4; ++pass) {
    int shift = 24 - pass * 8;
    if (t < 256) hist[t] = 0u;
    __syncthreads();
    unsigned prefix = s_state[0];
    unsigned need = s_state[1];
    unsigned pmask = pass ? (0xFFFFFFFFu << (shift + 8)) : 0u;
    for (int i = t; i < n; i += 1024) {
      unsigned kk = keys[i];
      if ((kk & pmask) == prefix) atomicAdd(&hist[(kk >> shift) & 255u], 1u);
    }
    __syncthreads();
    if (w == 0) {
      unsigned h[4], suf[4];
#pragma unroll
      for (int r = 0; r < 4; ++r) h[r] = hist[lane * 4 + r];
      suf[3] = h[3]; suf[2] = h[2] + suf[3]; suf[1] = h[1] + suf[2]; suf[0] = h[0] + suf[1];
      unsigned lsum = suf[0];
      unsigned s = lsum;
#pragma unroll
      for (int off = 1; off < 64; off <<= 1) {
        unsigned o = __shfl_down(s, off);
        if (lane + off < 64) s += o;
      }
      unsigned Hl = s - lsum;
      int cand = -1; unsigned cumAt = 0, histAt = 0;
#pragma unroll
      for (int r = 0; r < 4; ++r) {
        unsigned c = Hl + suf[r];
        if (c >= need) { cand = lane * 4 + r; cumAt = c; histAt = h[r]; }
      }
      int gmax = cand;
#pragma unroll
      for (int off = 32; off > 0; off >>= 1) {
        int o = __shfl_xor(gmax, off);
        gmax = o > gmax ? o : gmax;
      }
      if (cand == gmax && cand >= 0) {
        s_state[0] = prefix | ((unsigned)cand << shift);
        s_state[1] = need - (cumAt - histAt);
      }
    }
    __syncthreads();
  }
  unsigned cutoff = s_state[0];
  unsigned tcount = s_state[1];
  unsigned G = (unsigned)k - tcount;

  int i0 = t * 4;
  unsigned loc[4], cnt = 0;
#pragma unroll
  for (int r = 0; r < 4; ++r) {
    unsigned kk = keys[i0 + r];
    unsigned g = (kk > cutoff) ? 1u : 0u;
    unsigned e = (kk == cutoff) ? 1u : 0u;
    loc[r] = cnt;
    cnt += (g << 16) | e;
  }
  unsigned inc = cnt;
#pragma unroll
  for (int off = 1; off < 64; off <<= 1) {
    unsigned o = __shfl_up(inc, off);
    if (lane >= off) inc += o;
  }
  if (lane == 63) woff[w] = inc;
  __syncthreads();
  if (t == 0) {
    unsigned run = 0;
    for (int q = 0; q < 16; ++q) { unsigned v = woff[q]; woff[q] = run; run += v; }
  }
  __syncthreads();
  unsigned base = woff[w] + (inc - cnt);
#pragma unroll
  for (int r = 0; r < 4; ++r) {
    unsigned kk = keys[i0 + r];
    unsigned p = base + loc[r];
    if (kk > cutoff) {
      unsigned pos = p >> 16;
      perm[pos] = i0 + r; vals[pos] = decf(kk);
    } else if (kk == cutoff) {
      unsigned pe = p & 0xffffu;
      if (pe < tcount) { perm[G + pe] = i0 + r; vals[G + pe] = decf(kk); }
    }
  }
}

// ---------- fused gather + readout partials + last-block finalize ----------
__global__ __launch_bounds__(256) void k_gxp(const float* xg, const int* perm, const float* vals,
                                             float* xp, float* pmax, float* psum,
                                             int* cnt, float* out, int k) {
  __shared__ int isLast;
  int b = blockIdx.x, t = threadIdx.x;
  float m = -1e30f, s = 0.f;
  for (int r = b; r < k; r += RB) {
    float v = xg[(size_t)perm[r] * 256 + t] * vals[r];
    xp[(size_t)r * 256 + t] = v;
    m = fmaxf(m, v); s += v;
  }
  pmax[b * 256 + t] = m; psum[b * 256 + t] = s;
  __threadfence();
  __syncthreads();
  if (t == 0) isLast = (atomicAdd(cnt, 1) == RB - 1);
  __syncthreads();
  if (isLast) {
    float fm = -1e30f, fs = 0.f;
    for (int q = 0; q < RB; ++q) { fm = fmaxf(fm, pmax[q * 256 + t]); fs += psum[q * 256 + t]; }
    out[t] += fm;
    out[256 + t] += fs / (float)k;
  }
}

// ---------- ATnew[c][r] = ATold[perm[c]][perm[r]]  + deg for next layer ----------
// Fast path: degCur[sperm[c]]==0 -> source row all-zero -> vectorized zero writes.
__global__ __launch_bounds__(256) void k_gatherA(const unsigned char* ATold, const int* perm,
                                                 const int* degCur,
                                                 unsigned char* ATnew, int* degNext,
                                                 int nold, int kn) {
  __shared__ int sperm[4096];
  __shared__ int redi[256];
  int t = threadIdx.x, c = blockIdx.x;
  for (int r = t; r < kn; r += 256) sperm[r] = perm[r];
  __syncthreads();
  int src = sperm[c];
  unsigned char* orow = ATnew + (size_t)c * kn;
  if (degCur[src] == 0) {  // empty source row (kn % 16 == 0)
    uint4 z = make_uint4(0u, 0u, 0u, 0u);
    for (int r = t; r < kn / 16; r += 256) ((uint4*)orow)[r] = z;
    if (t == 0) degNext[c] = 0;
    return;
  }
  const unsigned char* row = ATold + (size_t)src * nold;
  int cnt = 0;
  for (int r = t; r < kn; r += 256) { unsigned char v = row[sperm[r]]; orow[r] = v; cnt += v; }
  redi[t] = cnt; __syncthreads();
  for (int s = 128; s > 0; s >>= 1) { if (t < s) redi[t] += redi[t + s]; __syncthreads(); }
  if (t == 0) degNext[c] = redi[0];
}

// ---------- host-side layer driver ----------
static void run_layer(hipStream_t stream, const float* x_in, int n, int inC,
                      const float* W, const float* b, const float* Wpool, const float* bpool,
                      int k, const unsigned char* ATcur, unsigned char* ATnext,
                      const int* degCur, int* degNext, int* cnt,
                      float* ybuf, float* xg, float* xp, float* y2,
                      float* score, int* perm, float* vals, float* pmax, float* psum, float* out) {
  k_gemm<<<(n / 32) * 4, 256, 0, stream>>>(x_in, W, degCur, ybuf, n, 256, inC);
  k_agg<<<n, 256, 0, stream>>>(ybuf, ATcur, degCur, b, Wpool, xg, y2, n);
  k_scorek<<<n / 4, 256, 0, stream>>>(y2, ATcur, degCur, bpool, score, n);
  k_topsel<<<1, 1024, 0, stream>>>(score, n, k, perm, vals);
  k_gxp<<<RB, 256, 0, stream>>>(xg, perm, vals, xp, pmax, psum, cnt, out, k);
  if (ATnext) k_gatherA<<<k, 256, 0, stream>>>(ATcur, perm, degCur, ATnext, degNext, n, k);
}

extern "C" void kernel_launch(void* const* d_in, const int* in_sizes, int n_in,
                              void* d_out, int out_size, void* d_ws, size_t ws_size,
                              hipStream_t stream) {
  const float* feature = (const float*)d_in[0];
  const float* img     = (const float*)d_in[1];
  const float* Wp      = (const float*)d_in[2];
  const float* bp      = (const float*)d_in[3];
  const float* ln_f_g  = (const float*)d_in[4];
  const float* ln_f_b  = (const float*)d_in[5];
  const float* ln_p_g  = (const float*)d_in[6];
  const float* ln_p_b  = (const float*)d_in[7];
  const float* W1 = (const float*)d_in[8];   const float* b1 = (const float*)d_in[9];
  const float* Wpool1 = (const float*)d_in[10]; const float* bpool1 = (const float*)d_in[11];
  const float* W2 = (const float*)d_in[12];  const float* b2 = (const float*)d_in[13];
  const float* Wpool2 = (const float*)d_in[14]; const float* bpool2 = (const float*)d_in[15];
  const float* W3 = (const float*)d_in[16];  const float* b3 = (const float*)d_in[17];
  const float* Wpool3 = (const float*)d_in[18]; const float* bpool3 = (const float*)d_in[19];
  float* out = (float*)d_out;
  (void)in_sizes; (void)n_in; (void)out_size; (void)ws_size;

  char* w = (char*)d_ws;
  size_t off = 0;
  auto alloc = [&](size_t bytes) -> char* {
    off = (off + 255) & ~(size_t)255;
    char* p = w + off;
    off += bytes;
    return p;
  };
  float* pos0 = (float*)alloc((size_t)NN * 12 * 4);
  float* x0   = (float*)alloc((size_t)NN * 512 * 4);
  unsigned short* x0h = (unsigned short*)alloc((size_t)NN * 512 * 2);
  float* sqv  = (float*)alloc((size_t)NN * 4);
  unsigned* dmax = (unsigned*)alloc(4);
  float* tileMin = (float*)alloc(528 * 4);
  int* degA = (int*)alloc((size_t)NN * 4);
  int* degB = (int*)alloc((size_t)NN * 4);
  int* cnt  = (int*)alloc(3 * 4);
  float* ybuf = (float*)alloc((size_t)NN * 256 * 4);
  float* xg   = (float*)alloc((size_t)NN * 256 * 4);
  float* xp   = (float*)alloc((size_t)NN * 256 * 4);
  float* y2   = (float*)alloc((size_t)NN * 4);
  float* score= (float*)alloc((size_t)NN * 4);
  int*   perm = (int*)alloc((size_t)NN * 4);
  float* vals = (float*)alloc((size_t)NN * 4);
  float* pmax = (float*)alloc(RB * 256 * 4);
  float* psum = (float*)alloc(RB * 256 * 4);
  unsigned char* ATa = (unsigned char*)alloc((size_t)NN * NN);
  unsigned char* ATb = (unsigned char*)alloc((size_t)3072 * 3072);

  // preamble (init fused into k_pos; LN/sq/cvt fused into k_attnln)
  k_pos<<<(NN * 12 + 255) / 256, 256, 0, stream>>>(img, Wp, bp, pos0, out, dmax, cnt);
  k_attnln<<<NN / 8, 256, 0, stream>>>(pos0, feature, ln_f_g, ln_f_b, ln_p_g, ln_p_b,
                                       x0, x0h, sqv, degA);

  // edge construction via MFMA: max+tileMin pass, then pruned mask pass (+deg atomics)
  const int NT = NN / 128, TT = NT * (NT + 1) / 2;  // 32, 528
  k_d2m<false><<<TT, 256, 0, stream>>>(x0h, sqv, dmax, tileMin, nullptr, nullptr);
  k_d2m<true><<<TT, 256, 0, stream>>>(x0h, sqv, dmax, tileMin, ATa, degA);

  // three GCN + SAGPool + readout layers
  run_layer(stream, x0, 4096, 512, W1, b1, Wpool1, bpool1, 3072, ATa, ATb,
            degA, degB, cnt + 0, ybuf, xg, xp, y2, score, perm, vals, pmax, psum, out);
  run_layer(stream, xp, 3072, 256, W2, b2, Wpool2, bpool2, 2304, ATb, ATa,
            degB, degA, cnt + 1, ybuf, xg, xp, y2, score, perm, vals, pmax, psum, out);
  run_layer(stream, xp, 2304, 256, W3, b3, Wpool3, bpool3, 1728, ATa, nullptr,
            degA, nullptr, cnt + 2, ybuf, xg, xp, y2, score, perm, vals, pmax, psum, out);
}

// Round 15
// 232.724 us; speedup vs baseline: 1.1067x; 1.1067x over previous
//
#include <hip/hip_runtime.h>
#include <math.h>

#define NN 4096
#define RB 128  // readout stage-1 blocks

typedef __attribute__((ext_vector_type(8))) short bf16x8;
typedef __attribute__((ext_vector_type(4))) float f32x4;

// ---------- helpers ----------
__device__ __forceinline__ unsigned encf(float f) {
  unsigned u = __float_as_uint(f);
  return (u & 0x80000000u) ? ~u : (u | 0x80000000u);
}
__device__ __forceinline__ float decf(unsigned u) {
  return __uint_as_float((u & 0x80000000u) ? (u ^ 0x80000000u) : ~u);
}
__device__ __forceinline__ unsigned short f2bf(float f) {
  unsigned u = __float_as_uint(f);
  return (unsigned short)((u + 0x7fffu + ((u >> 16) & 1u)) >> 16);
}

// ---------- pos = img @ Wp + bp  (+ init out/dmax in block 0) ----------
__global__ void k_pos(const float* img, const float* Wp, const float* bp, float* pos,
                      float* out, unsigned* dmax) {
  if (blockIdx.x == 0) {
    int tt = threadIdx.x;
    out[tt] = 0.f; out[256 + tt] = 0.f;
    if (tt == 0) *dmax = 0u;
  }
  int t = blockIdx.x * 256 + threadIdx.x;
  if (t >= NN * 12) return;
  int i = t / 12, d = t % 12;
  float s = bp[d];
#pragma unroll
  for (int k = 0; k < 6; ++k) s += img[i * 6 + k] * Wp[k * 12 + d];
  pos[t] = s;
}

// ---------- attention, d=12, LDS-tiled keys, branch-free softmax (R13-proven) ----------
__global__ __launch_bounds__(256) void k_attn3(const float* pos, float* out) {
  __shared__ float sp[12][256];
  int t = threadIdx.x, lane = t & 63, w = t >> 6;
  int ib = blockIdx.x * 8 + w * 2;  // 2 rows per wave, 8 per block
  float pi[2][12];
#pragma unroll
  for (int r = 0; r < 2; ++r)
#pragma unroll
    for (int d = 0; d < 12; ++d) pi[r][d] = pos[(ib + r) * 12 + d] * 0.28867513459481287f;
  float sl[2] = {0.f, 0.f};
  float acc[2][12] = {};
  const float4* p4 = (const float4*)pos;
  for (int kt = 0; kt < NN; kt += 256) {
    __syncthreads();  // previous tile fully consumed
    int j = kt + t;
    float4 a = p4[j * 3 + 0], b = p4[j * 3 + 1], c = p4[j * 3 + 2];
    sp[0][t] = a.x; sp[1][t] = a.y; sp[2][t] = a.z; sp[3][t] = a.w;
    sp[4][t] = b.x; sp[5][t] = b.y; sp[6][t] = b.z; sp[7][t] = b.w;
    sp[8][t] = c.x; sp[9][t] = c.y; sp[10][t] = c.z; sp[11][t] = c.w;
    __syncthreads();
#pragma unroll
    for (int q = 0; q < 4; ++q) {
      int jj = q * 64 + lane;
      float pj[12];
#pragma unroll
      for (int d = 0; d < 12; ++d) pj[d] = sp[d][jj];
#pragma unroll
      for (int r = 0; r < 2; ++r) {
        float s = 0.f;
#pragma unroll
        for (int d = 0; d < 12; ++d) s = fmaf(pi[r][d], pj[d], s);
        float e = __expf(s);
        sl[r] += e;
#pragma unroll
        for (int d = 0; d < 12; ++d) acc[r][d] = fmaf(e, pj[d], acc[r][d]);
      }
    }
  }
#pragma unroll
  for (int r = 0; r < 2; ++r) {
    float s = sl[r];
#pragma unroll
    for (int o = 32; o > 0; o >>= 1) s += __shfl_xor(s, o);
    float ad[12];
#pragma unroll
    for (int d = 0; d < 12; ++d) {
      ad[d] = acc[r][d];
#pragma unroll
      for (int o = 32; o > 0; o >>= 1) ad[d] += __shfl_xor(ad[d], o);
    }
    if (lane == 0) {
      float inv = 1.f / s;
#pragma unroll
      for (int d = 0; d < 12; ++d) out[(ib + r) * 12 + d] = ad[d] * inv;
    }
  }
}

// ---------- fused layernorms + sumsq + bf16 convert (R13-proven) + deg zero ----------
__global__ __launch_bounds__(256) void k_lnx(const float* f, const float* g, const float* b,
                                             const float* p, const float* pg, const float* pb,
                                             float* x0, unsigned short* x0h, float* sqv,
                                             int* degA) {
  __shared__ float row[512];
  __shared__ float red[256];
  int i = blockIdx.x, t = threadIdx.x;
  if (t == 0) degA[i] = 0;
  float v1 = f[i * 500 + t];
  float v2 = (t < 244) ? f[i * 500 + 256 + t] : 0.f;
  red[t] = v1 + v2; __syncthreads();
  for (int s = 128; s > 0; s >>= 1) { if (t < s) red[t] += red[t + s]; __syncthreads(); }
  float m = red[0] * (1.f / 500.f); __syncthreads();
  float d1 = v1 - m, d2 = v2 - m;
  red[t] = d1 * d1 + ((t < 244) ? d2 * d2 : 0.f); __syncthreads();
  for (int s = 128; s > 0; s >>= 1) { if (t < s) red[t] += red[t + s]; __syncthreads(); }
  float scale = 1.f / sqrtf(red[0] * (1.f / 500.f) + 1e-5f);
  row[t] = d1 * scale * g[t] + b[t];
  if (t < 244) row[256 + t] = d2 * scale * g[256 + t] + b[256 + t];
  if (t >= 244) {  // threads 244..255 handle the 12-wide pos layernorm
    int tt = t - 244;
    float pv[12], pm = 0.f;
#pragma unroll
    for (int d = 0; d < 12; ++d) { pv[d] = p[i * 12 + d]; pm += pv[d]; }
    pm *= (1.f / 12.f);
    float pvar = 0.f;
#pragma unroll
    for (int d = 0; d < 12; ++d) { float dd = pv[d] - pm; pvar += dd * dd; }
    pvar *= (1.f / 12.f);
    float ps = 1.f / sqrtf(pvar + 1e-5f);
    row[500 + tt] = (pv[tt] - pm) * ps * pg[tt] + pb[tt];
  }
  __syncthreads();
  float a = row[t], c = row[256 + t];
  red[t] = a * a + c * c; __syncthreads();
  for (int s = 128; s > 0; s >>= 1) { if (t < s) red[t] += red[t + s]; __syncthreads(); }
  if (t == 0) sqv[i] = red[0];
  x0[(size_t)i * 512 + t] = a;
  x0[(size_t)i * 512 + 256 + t] = c;
  x0h[(size_t)i * 512 + t] = f2bf(a);
  x0h[(size_t)i * 512 + 256 + t] = f2bf(c);
}

// ---------- MFMA d2 tiles (128x128, upper tile pairs): max / mask pass ----------
// T4 pipeline (m201 pattern): double-buffered LDS; issue next panel's 8 DMAs, then
// COUNTED s_waitcnt vmcnt(8), sched_barrier(0), raw s_barrier. No vmcnt(0) drain.
// Source pre-swizzled (chunk = (lane&7)^(row&7)); reads apply the same XOR.
// Pass A records per-tile min over gi<gj; pass B skips GEMM when tileMin >= thr,
// zeroes mirror tiles, and atomically accumulates integer deg[j] (0 atomics if empty).
#define BK 64
template <bool MASK>
__global__ __launch_bounds__(256) void k_d2m(const unsigned short* X, const float* sqv,
                                             unsigned* dmax, float* tileMin,
                                             unsigned char* ATm, int* deg) {
  __shared__ unsigned short As[2][128 * BK];
  __shared__ unsigned short Bs[2][128 * BK];
  __shared__ float wmax[4], wmin[4];
  const int NT = NN / 128;
  int bid0 = blockIdx.x;
  int bid = (bid0 & 7) * 66 + (bid0 >> 3);  // 528 total, bijective
  int ti = 0, rem = bid;
  while (rem >= NT - ti) { rem -= NT - ti; ++ti; }
  int tj = ti + rem;
  int t = threadIdx.x, lane = t & 63, w = t >> 6;
  int wr = w >> 1, wc = w & 1;  // wave's 64x64 sub-tile
  const unsigned short* Abase = X + (size_t)ti * 128 * 512;
  const unsigned short* Bbase = X + (size_t)tj * 128 * 512;
  int lr = lane >> 3, lc = lane & 7;

  float thr = 0.f;
  if (MASK) {
    thr = 0.5f * decf(*dmax);
    uint4 z = make_uint4(0u, 0u, 0u, 0u);
    if (ti != tj) {  // mirror tile (rows ti, cols tj) never receives mask writes
#pragma unroll
      for (int q0 = 0; q0 < 4; ++q0) {
        int q = t + q0 * 256; int r = q >> 3, c4 = q & 7;
        *(uint4*)(ATm + (size_t)(ti * 128 + r) * NN + tj * 128 + c4 * 16) = z;
      }
    }
    if (tileMin[blockIdx.x] >= thr) {  // no element can pass -> zero tile, skip GEMM
#pragma unroll
      for (int q0 = 0; q0 < 4; ++q0) {
        int q = t + q0 * 256; int r = q >> 3, c4 = q & 7;
        *(uint4*)(ATm + (size_t)(tj * 128 + r) * NN + ti * 128 + c4 * 16) = z;
      }
      return;
    }
  }

  auto stage = [&](int buf, int k0) {  // 8 DMAs per wave (4x A + 4x B)
#pragma unroll
    for (int i = 0; i < 4; ++i) {
      int q = w * 4 + i;
      int r = q * 8 + lr;
      int cs = lc ^ (r & 7);  // pre-swizzled source chunk
      __builtin_amdgcn_global_load_lds(
          (const __attribute__((address_space(1))) unsigned int*)(Abase + (size_t)r * 512 + k0 + cs * 8),
          (__attribute__((address_space(3))) unsigned int*)(&As[buf][q * 512]), 16, 0, 0);
      __builtin_amdgcn_global_load_lds(
          (const __attribute__((address_space(1))) unsigned int*)(Bbase + (size_t)r * 512 + k0 + cs * 8),
          (__attribute__((address_space(3))) unsigned int*)(&Bs[buf][q * 512]), 16, 0, 0);
    }
  };

  stage(0, 0);  // 8 outstanding

  f32x4 acc[4][4] = {};
  int rl = lane & 15, kg = lane >> 4;
  for (int step = 0; step < 8; ++step) {
    int cur = step & 1;
    if (step < 7) {
      stage(cur ^ 1, (step + 1) * BK);  // +8 in flight (16 total)
      asm volatile("s_waitcnt vmcnt(8)" ::: "memory");  // cur's 8 retired (in-order)
    } else {
      asm volatile("s_waitcnt vmcnt(0)" ::: "memory");
    }
    __builtin_amdgcn_sched_barrier(0);
    __builtin_amdgcn_s_barrier();  // all waves' cur panel visible
#pragma unroll
    for (int ks = 0; ks < 2; ++ks) {
      bf16x8 af[4], bq[4];
#pragma unroll
      for (int f = 0; f < 4; ++f) {
        int rA = wr * 64 + f * 16 + rl;
        af[f] = *(const bf16x8*)(&As[cur][rA * BK + (((ks * 4 + kg) ^ (rA & 7)) << 3)]);
        int rB = wc * 64 + f * 16 + rl;
        bq[f] = *(const bf16x8*)(&Bs[cur][rB * BK + (((ks * 4 + kg) ^ (rB & 7)) << 3)]);
      }
#pragma unroll
      for (int a = 0; a < 4; ++a)
#pragma unroll
        for (int b = 0; b < 4; ++b)
          acc[a][b] = __builtin_amdgcn_mfma_f32_16x16x32_bf16(af[a], bq[b], acc[a][b], 0, 0, 0);
    }
    __builtin_amdgcn_sched_barrier(0);  // pin ds_reads before the reuse barrier
    __builtin_amdgcn_s_barrier();       // all reads of cur done before its overwrite
  }
  // C/D layout: col = lane&15, row = (lane>>4)*4 + reg   [m89/m91 verified]
  int rbase = ti * 128 + wr * 64 + ((lane >> 4) << 2);
  int cbase = tj * 128 + wc * 64 + (lane & 15);
  if (!MASK) {
    float lm = -1e30f, lmin = 1e30f;
#pragma unroll
    for (int a = 0; a < 4; ++a) {
      float si[4];
#pragma unroll
      for (int r = 0; r < 4; ++r) si[r] = sqv[rbase + a * 16 + r];
#pragma unroll
      for (int b = 0; b < 4; ++b) {
        int gj = cbase + b * 16;
        float sj = sqv[gj];
#pragma unroll
        for (int r = 0; r < 4; ++r) {
          float d2v = si[r] - 2.f * acc[a][b][r] + sj;
          lm = fmaxf(lm, d2v);
          if (rbase + a * 16 + r < gj) lmin = fminf(lmin, d2v);
        }
      }
    }
#pragma unroll
    for (int o = 32; o > 0; o >>= 1) {
      lm = fmaxf(lm, __shfl_xor(lm, o));
      lmin = fminf(lmin, __shfl_xor(lmin, o));
    }
    if (lane == 0) { wmax[w] = lm; wmin[w] = lmin; }
    __syncthreads();
    if (t == 0) {
      atomicMax(dmax, encf(fmaxf(fmaxf(wmax[0], wmax[1]), fmaxf(wmax[2], wmax[3]))));
      tileMin[blockIdx.x] = fminf(fminf(wmin[0], wmin[1]), fminf(wmin[2], wmin[3]));
    }
  } else {
#pragma unroll
    for (int b = 0; b < 4; ++b) {
      int gj = cbase + b * 16;
      float sj = sqv[gj];
      int rowcnt = 0;
#pragma unroll
      for (int a = 0; a < 4; ++a) {
        int gi0 = rbase + a * 16;
        union { unsigned char c[4]; unsigned u; } m4;
#pragma unroll
        for (int r = 0; r < 4; ++r) {
          float d2v = sqv[gi0 + r] - 2.f * acc[a][b][r] + sj;
          unsigned char mv = (d2v < thr && (gi0 + r) < gj) ? 1 : 0;
          m4.c[r] = mv; rowcnt += mv;
        }
        *(unsigned*)(ATm + (size_t)gj * NN + gi0) = m4.u;  // AT[j][i..i+3]
      }
      if (rowcnt) atomicAdd(&deg[gj], rowcnt);
    }
  }
}

// ---------- fp32 GEMM + row scale: C[i][c] = (A@B)[i][c] / sqrt(1+deg[i]) ----------
__global__ __launch_bounds__(256) void k_gemm(const float* A, const float* B, const int* deg,
                                              float* C, int M, int N, int K) {
  __shared__ float As[32][17];
  __shared__ float Bs[16][64];
  int t = threadIdx.x, tx = t & 15, ty = t >> 4;
  int nbx = N >> 6;
  int total = gridDim.x;
  int bid0 = blockIdx.x;
  int bid = (bid0 & 7) * (total >> 3) + (bid0 >> 3);  // bijective: total%8==0
  int m0 = (bid / nbx) * 32, n0 = (bid % nbx) * 64;
  int ar = t >> 3, ac = (t * 2) & 15;   // A stage: 2 floats/thread
  int br = t >> 4, bc = (t & 15) * 4;   // B stage: 4 floats/thread
  float2 ra = *(const float2*)(A + (size_t)(m0 + ar) * K + ac);
  float4 rb = *(const float4*)(B + (size_t)br * N + n0 + bc);
  float acc[2][4] = {};
  for (int k0 = 0; k0 < K; k0 += 16) {
    As[ar][ac] = ra.x; As[ar][ac + 1] = ra.y;
    *(float4*)(&Bs[br][bc]) = rb;
    __syncthreads();
    if (k0 + 16 < K) {  // prefetch next panel (overlaps compute)
      ra = *(const float2*)(A + (size_t)(m0 + ar) * K + k0 + 16 + ac);
      rb = *(const float4*)(B + (size_t)(k0 + 16 + br) * N + n0 + bc);
    }
#pragma unroll
    for (int kk = 0; kk < 16; ++kk) {
      float av[2], bv[4];
#pragma unroll
      for (int u = 0; u < 2; ++u) av[u] = As[ty * 2 + u][kk];
#pragma unroll
      for (int u = 0; u < 4; ++u) bv[u] = Bs[kk][tx * 4 + u];
#pragma unroll
      for (int a = 0; a < 2; ++a)
#pragma unroll
        for (int b2 = 0; b2 < 4; ++b2) acc[a][b2] = fmaf(av[a], bv[b2], acc[a][b2]);
    }
    __syncthreads();
  }
#pragma unroll
  for (int a = 0; a < 2; ++a) {
    float dv = 1.f / sqrtf((float)(1 + deg[m0 + ty * 2 + a]));
#pragma unroll
    for (int b2 = 0; b2 < 4; ++b2)
      C[(size_t)(m0 + ty * 2 + a) * N + n0 + tx * 4 + b2] = acc[a][b2] * dv;
  }
}

// ---------- fused: xg row + relu + y2[j] = dinv[j]*dot(xg[j], Wpool) ----------
// Fast path: deg[j]==0 -> no neighbors, skip the mask scan (exact).
__global__ __launch_bounds__(256) void k_agg(const float* y, const unsigned char* ATm,
                                             const int* deg, const float* bias,
                                             const float* Wpool, float* out, float* y2, int n) {
  __shared__ unsigned char mrow[256];
  __shared__ int s_any;
  __shared__ float red[256];
  int j = blockIdx.x, t = threadIdx.x;
  int dg = deg[j];
  float dj = 1.f / sqrtf((float)(1 + dg));
  float acc = y[(size_t)j * 256 + t];
  if (dg != 0) {
    for (int i0 = 0; i0 < n; i0 += 256) {
      if (t == 0) s_any = 0;
      __syncthreads();
      unsigned char m = ATm[(size_t)j * n + i0 + t];
      mrow[t] = m;
      if (m) s_any = 1;
      __syncthreads();
      if (s_any) {
        for (int u = 0; u < 256; ++u)
          if (mrow[u]) acc += y[(size_t)(i0 + u) * 256 + t];
      }
      __syncthreads();
    }
  }
  float o = fmaxf(dj * acc + bias[t], 0.f);
  out[(size_t)j * 256 + t] = o;
  red[t] = o * Wpool[t]; __syncthreads();
  for (int s = 128; s > 0; s >>= 1) { if (t < s) red[t] += red[t + s]; __syncthreads(); }
  if (t == 0) y2[j] = dj * red[0];
}

// ---------- score[j] = tanh(dinv[j]*(y2[j] + sum_{i:AT[j,i]} y2[i]) + bpool) ----------
__global__ __launch_bounds__(256) void k_scorek(const float* y2, const unsigned char* ATm,
                                                const int* deg, const float* bp,
                                                float* score, int n) {
  int w = threadIdx.x >> 6, lane = threadIdx.x & 63;
  int j = blockIdx.x * 4 + w;
  if (j >= n) return;
  int dg = deg[j];
  float dj = 1.f / sqrtf((float)(1 + dg));
  float s = 0.f;
  if (dg != 0) {  // deg>0: scan the row
    const uint4* row = (const uint4*)(ATm + (size_t)j * n);
    for (int p = lane; p < n / 16; p += 64) {
      uint4 v = row[p];
      if (v.x | v.y | v.z | v.w) {
        int base = p * 16;
#pragma unroll
        for (int q = 0; q < 4; ++q) {
          unsigned u = (&v.x)[q];
#pragma unroll
          for (int b2 = 0; b2 < 4; ++b2)
            if ((u >> (8 * b2)) & 0xffu) s += y2[base + q * 4 + b2];
        }
      }
    }
    for (int sh = 32; sh > 0; sh >>= 1) s += __shfl_down(s, sh);
  }
  if (lane == 0) score[j] = tanhf(dj * (y2[j] + s) + bp[0]);
}

// ---------- radix-select top-k (exact PyG set semantics; output in index order) ----------
__global__ __launch_bounds__(1024) void k_topsel(const float* score, int n, int k,
                                                 int* perm, float* vals) {
  __shared__ unsigned keys[4096];
  __shared__ unsigned hist[256];
  __shared__ unsigned s_state[2];  // [0]=prefix(cutoff), [1]=need(ties to take)
  __shared__ unsigned woff[16];
  int t = threadIdx.x, lane = t & 63, w = t >> 6;
  for (int i = t; i < 4096; i += 1024) keys[i] = (i < n) ? encf(score[i]) : 0u;
  if (t == 0) { s_state[0] = 0u; s_state[1] = (unsigned)k; }
  __syncthreads();

  for (int pass = 0; pass < 4; ++pass) {
    int shift = 24 - pass * 8;
    if (t < 256) hist[t] = 0u;
    __syncthreads();
    unsigned prefix = s_state[0];
    unsigned need = s_state[1];
    unsigned pmask = pass ? (0xFFFFFFFFu << (shift + 8)) : 0u;
    for (int i = t; i < n; i += 1024) {
      unsigned kk = keys[i];
      if ((kk & pmask) == prefix) atomicAdd(&hist[(kk >> shift) & 255u], 1u);
    }
    __syncthreads();
    if (w == 0) {
      unsigned h[4], suf[4];
#pragma unroll
      for (int r = 0; r < 4; ++r) h[r] = hist[lane * 4 + r];
      suf[3] = h[3]; suf[2] = h[2] + suf[3]; suf[1] = h[1] + suf[2]; suf[0] = h[0] + suf[1];
      unsigned lsum = suf[0];
      unsigned s = lsum;
#pragma unroll
      for (int off = 1; off < 64; off <<= 1) {
        unsigned o = __shfl_down(s, off);
        if (lane + off < 64) s += o;
      }
      unsigned Hl = s - lsum;
      int cand = -1; unsigned cumAt = 0, histAt = 0;
#pragma unroll
      for (int r = 0; r < 4; ++r) {
        unsigned c = Hl + suf[r];
        if (c >= need) { cand = lane * 4 + r; cumAt = c; histAt = h[r]; }
      }
      int gmax = cand;
#pragma unroll
      for (int off = 32; off > 0; off >>= 1) {
        int o = __shfl_xor(gmax, off);
        gmax = o > gmax ? o : gmax;
      }
      if (cand == gmax && cand >= 0) {
        s_state[0] = prefix | ((unsigned)cand << shift);
        s_state[1] = need - (cumAt - histAt);
      }
    }
    __syncthreads();
  }
  unsigned cutoff = s_state[0];
  unsigned tcount = s_state[1];
  unsigned G = (unsigned)k - tcount;

  int i0 = t * 4;
  unsigned loc[4], cnt = 0;
#pragma unroll
  for (int r = 0; r < 4; ++r) {
    unsigned kk = keys[i0 + r];
    unsigned g = (kk > cutoff) ? 1u : 0u;
    unsigned e = (kk == cutoff) ? 1u : 0u;
    loc[r] = cnt;
    cnt += (g << 16) | e;
  }
  unsigned inc = cnt;
#pragma unroll
  for (int off = 1; off < 64; off <<= 1) {
    unsigned o = __shfl_up(inc, off);
    if (lane >= off) inc += o;
  }
  if (lane == 63) woff[w] = inc;
  __syncthreads();
  if (t == 0) {
    unsigned run = 0;
    for (int q = 0; q < 16; ++q) { unsigned v = woff[q]; woff[q] = run; run += v; }
  }
  __syncthreads();
  unsigned base = woff[w] + (inc - cnt);
#pragma unroll
  for (int r = 0; r < 4; ++r) {
    unsigned kk = keys[i0 + r];
    unsigned p = base + loc[r];
    if (kk > cutoff) {
      unsigned pos = p >> 16;
      perm[pos] = i0 + r; vals[pos] = decf(kk);
    } else if (kk == cutoff) {
      unsigned pe = p & 0xffffu;
      if (pe < tcount) { perm[G + pe] = i0 + r; vals[G + pe] = decf(kk); }
    }
  }
}

// ---------- fused gather + readout partials ----------
__global__ __launch_bounds__(256) void k_gxp(const float* xg, const int* perm, const float* vals,
                                             float* xp, float* pmax, float* psum, int k) {
  int b = blockIdx.x, t = threadIdx.x;
  float m = -1e30f, s = 0.f;
  for (int r = b; r < k; r += RB) {
    float v = xg[(size_t)perm[r] * 256 + t] * vals[r];
    xp[(size_t)r * 256 + t] = v;
    m = fmaxf(m, v); s += v;
  }
  pmax[b * 256 + t] = m; psum[b * 256 + t] = s;
}
__global__ void k_rfin(const float* pmax, const float* psum, float* out, int k) {
  int t = threadIdx.x;
  float m = -1e30f, s = 0.f;
  for (int q = 0; q < RB; ++q) { m = fmaxf(m, pmax[q * 256 + t]); s += psum[q * 256 + t]; }
  out[t] += m;
  out[256 + t] += s / (float)k;
}

// ---------- ATnew[c][r] = ATold[perm[c]][perm[r]]  + deg for next layer ----------
// Fast path: degCur[sperm[c]]==0 -> source row all-zero -> vectorized zero writes.
__global__ __launch_bounds__(256) void k_gatherA(const unsigned char* ATold, const int* perm,
                                                 const int* degCur,
                                                 unsigned char* ATnew, int* degNext,
                                                 int nold, int kn) {
  __shared__ int sperm[4096];
  __shared__ int redi[256];
  int t = threadIdx.x, c = blockIdx.x;
  for (int r = t; r < kn; r += 256) sperm[r] = perm[r];
  __syncthreads();
  int src = sperm[c];
  unsigned char* orow = ATnew + (size_t)c * kn;
  if (degCur[src] == 0) {  // empty source row (kn % 16 == 0)
    uint4 z = make_uint4(0u, 0u, 0u, 0u);
    for (int r = t; r < kn / 16; r += 256) ((uint4*)orow)[r] = z;
    if (t == 0) degNext[c] = 0;
    return;
  }
  const unsigned char* row = ATold + (size_t)src * nold;
  int cnt = 0;
  for (int r = t; r < kn; r += 256) { unsigned char v = row[sperm[r]]; orow[r] = v; cnt += v; }
  redi[t] = cnt; __syncthreads();
  for (int s = 128; s > 0; s >>= 1) { if (t < s) redi[t] += redi[t + s]; __syncthreads(); }
  if (t == 0) degNext[c] = redi[0];
}

// ---------- host-side layer driver ----------
static void run_layer(hipStream_t stream, const float* x_in, int n, int inC,
                      const float* W, const float* b, const float* Wpool, const float* bpool,
                      int k, const unsigned char* ATcur, unsigned char* ATnext,
                      const int* degCur, int* degNext,
                      float* ybuf, float* xg, float* xp, float* y2,
                      float* score, int* perm, float* vals, float* pmax, float* psum, float* out) {
  k_gemm<<<(n / 32) * 4, 256, 0, stream>>>(x_in, W, degCur, ybuf, n, 256, inC);
  k_agg<<<n, 256, 0, stream>>>(ybuf, ATcur, degCur, b, Wpool, xg, y2, n);
  k_scorek<<<n / 4, 256, 0, stream>>>(y2, ATcur, degCur, bpool, score, n);
  k_topsel<<<1, 1024, 0, stream>>>(score, n, k, perm, vals);
  k_gxp<<<RB, 256, 0, stream>>>(xg, perm, vals, xp, pmax, psum, k);
  k_rfin<<<1, 256, 0, stream>>>(pmax, psum, out, k);
  if (ATnext) k_gatherA<<<k, 256, 0, stream>>>(ATcur, perm, degCur, ATnext, degNext, n, k);
}

extern "C" void kernel_launch(void* const* d_in, const int* in_sizes, int n_in,
                              void* d_out, int out_size, void* d_ws, size_t ws_size,
                              hipStream_t stream) {
  const float* feature = (const float*)d_in[0];
  const float* img     = (const float*)d_in[1];
  const float* Wp      = (const float*)d_in[2];
  const float* bp      = (const float*)d_in[3];
  const float* ln_f_g  = (const float*)d_in[4];
  const float* ln_f_b  = (const float*)d_in[5];
  const float* ln_p_g  = (const float*)d_in[6];
  const float* ln_p_b  = (const float*)d_in[7];
  const float* W1 = (const float*)d_in[8];   const float* b1 = (const float*)d_in[9];
  const float* Wpool1 = (const float*)d_in[10]; const float* bpool1 = (const float*)d_in[11];
  const float* W2 = (const float*)d_in[12];  const float* b2 = (const float*)d_in[13];
  const float* Wpool2 = (const float*)d_in[14]; const float* bpool2 = (const float*)d_in[15];
  const float* W3 = (const float*)d_in[16];  const float* b3 = (const float*)d_in[17];
  const float* Wpool3 = (const float*)d_in[18]; const float* bpool3 = (const float*)d_in[19];
  float* out = (float*)d_out;
  (void)in_sizes; (void)n_in; (void)out_size; (void)ws_size;

  char* w = (char*)d_ws;
  size_t off = 0;
  auto alloc = [&](size_t bytes) -> char* {
    off = (off + 255) & ~(size_t)255;
    char* p = w + off;
    off += bytes;
    return p;
  };
  float* pos0 = (float*)alloc((size_t)NN * 12 * 4);
  float* pos1 = (float*)alloc((size_t)NN * 12 * 4);
  float* x0   = (float*)alloc((size_t)NN * 512 * 4);
  unsigned short* x0h = (unsigned short*)alloc((size_t)NN * 512 * 2);
  float* sqv  = (float*)alloc((size_t)NN * 4);
  unsigned* dmax = (unsigned*)alloc(4);
  float* tileMin = (float*)alloc(528 * 4);
  int* degA = (int*)alloc((size_t)NN * 4);
  int* degB = (int*)alloc((size_t)NN * 4);
  float* ybuf = (float*)alloc((size_t)NN * 256 * 4);
  float* xg   = (float*)alloc((size_t)NN * 256 * 4);
  float* xp   = (float*)alloc((size_t)NN * 256 * 4);
  float* y2   = (float*)alloc((size_t)NN * 4);
  float* score= (float*)alloc((size_t)NN * 4);
  int*   perm = (int*)alloc((size_t)NN * 4);
  float* vals = (float*)alloc((size_t)NN * 4);
  float* pmax = (float*)alloc(RB * 256 * 4);
  float* psum = (float*)alloc(RB * 256 * 4);
  unsigned char* ATa = (unsigned char*)alloc((size_t)NN * NN);
  unsigned char* ATb = (unsigned char*)alloc((size_t)3072 * 3072);

  // preamble (init fused into k_pos; lnx zeroes degA)
  k_pos<<<(NN * 12 + 255) / 256, 256, 0, stream>>>(img, Wp, bp, pos0, out, dmax);
  k_attn3<<<NN / 8, 256, 0, stream>>>(pos0, pos1);
  k_lnx<<<NN, 256, 0, stream>>>(feature, ln_f_g, ln_f_b, pos1, ln_p_g, ln_p_b,
                                x0, x0h, sqv, degA);

  // edge construction via MFMA: max+tileMin pass, then pruned mask pass (+deg atomics)
  const int NT = NN / 128, TT = NT * (NT + 1) / 2;  // 32, 528
  k_d2m<false><<<TT, 256, 0, stream>>>(x0h, sqv, dmax, tileMin, nullptr, nullptr);
  k_d2m<true><<<TT, 256, 0, stream>>>(x0h, sqv, dmax, tileMin, ATa, degA);

  // three GCN + SAGPool + readout layers
  run_layer(stream, x0, 4096, 512, W1, b1, Wpool1, bpool1, 3072, ATa, ATb, degA, degB,
            ybuf, xg, xp, y2, score, perm, vals, pmax, psum, out);
  run_layer(stream, xp, 3072, 256, W2, b2, Wpool2, bpool2, 2304, ATb, ATa, degB, degA,
            ybuf, xg, xp, y2, score, perm, vals, pmax, psum, out);
  run_layer(stream, xp, 2304, 256, W3, b3, Wpool3, bpool3, 1728, ATa, nullptr, degA, nullptr,
            ybuf, xg, xp, y2, score, perm, vals, pmax, psum, out);
}

// Round 16
// 231.913 us; speedup vs baseline: 1.1105x; 1.0035x over previous
//
#include <hip/hip_runtime.h>
#include <math.h>

#define NN 4096
#define RB 128  // readout stage-1 blocks

typedef __attribute__((ext_vector_type(8))) short bf16x8;
typedef __attribute__((ext_vector_type(4))) float f32x4;

// ---------- helpers ----------
__device__ __forceinline__ unsigned encf(float f) {
  unsigned u = __float_as_uint(f);
  return (u & 0x80000000u) ? ~u : (u | 0x80000000u);
}
__device__ __forceinline__ float decf(unsigned u) {
  return __uint_as_float((u & 0x80000000u) ? (u ^ 0x80000000u) : ~u);
}
__device__ __forceinline__ unsigned short f2bf(float f) {
  unsigned u = __float_as_uint(f);
  return (unsigned short)((u + 0x7fffu + ((u >> 16) & 1u)) >> 16);
}

// ---------- pos = img @ Wp + bp  (+ init out/dmax in block 0) ----------
__global__ void k_pos(const float* img, const float* Wp, const float* bp, float* pos,
                      float* out, unsigned* dmax) {
  if (blockIdx.x == 0) {
    int tt = threadIdx.x;
    out[tt] = 0.f; out[256 + tt] = 0.f;
    if (tt == 0) *dmax = 0u;
  }
  int t = blockIdx.x * 256 + threadIdx.x;
  if (t >= NN * 12) return;
  int i = t / 12, d = t % 12;
  float s = bp[d];
#pragma unroll
  for (int k = 0; k < 6; ++k) s += img[i * 6 + k] * Wp[k * 12 + d];
  pos[t] = s;
}

// ---------- attention, d=12, LDS-tiled keys, branch-free softmax ----------
__global__ __launch_bounds__(256) void k_attn3(const float* pos, float* out) {
  __shared__ float sp[12][256];
  int t = threadIdx.x, lane = t & 63, w = t >> 6;
  int ib = blockIdx.x * 8 + w * 2;  // 2 rows per wave, 8 per block
  float pi[2][12];
#pragma unroll
  for (int r = 0; r < 2; ++r)
#pragma unroll
    for (int d = 0; d < 12; ++d) pi[r][d] = pos[(ib + r) * 12 + d] * 0.28867513459481287f;
  float sl[2] = {0.f, 0.f};
  float acc[2][12] = {};
  const float4* p4 = (const float4*)pos;
  for (int kt = 0; kt < NN; kt += 256) {
    __syncthreads();  // previous tile fully consumed
    int j = kt + t;
    float4 a = p4[j * 3 + 0], b = p4[j * 3 + 1], c = p4[j * 3 + 2];
    sp[0][t] = a.x; sp[1][t] = a.y; sp[2][t] = a.z; sp[3][t] = a.w;
    sp[4][t] = b.x; sp[5][t] = b.y; sp[6][t] = b.z; sp[7][t] = b.w;
    sp[8][t] = c.x; sp[9][t] = c.y; sp[10][t] = c.z; sp[11][t] = c.w;
    __syncthreads();
#pragma unroll
    for (int q = 0; q < 4; ++q) {
      int jj = q * 64 + lane;
      float pj[12];
#pragma unroll
      for (int d = 0; d < 12; ++d) pj[d] = sp[d][jj];
#pragma unroll
      for (int r = 0; r < 2; ++r) {
        float s = 0.f;
#pragma unroll
        for (int d = 0; d < 12; ++d) s = fmaf(pi[r][d], pj[d], s);
        float e = __expf(s);
        sl[r] += e;
#pragma unroll
        for (int d = 0; d < 12; ++d) acc[r][d] = fmaf(e, pj[d], acc[r][d]);
      }
    }
  }
#pragma unroll
  for (int r = 0; r < 2; ++r) {
    float s = sl[r];
#pragma unroll
    for (int o = 32; o > 0; o >>= 1) s += __shfl_xor(s, o);
    float ad[12];
#pragma unroll
    for (int d = 0; d < 12; ++d) {
      ad[d] = acc[r][d];
#pragma unroll
      for (int o = 32; o > 0; o >>= 1) ad[d] += __shfl_xor(ad[d], o);
    }
    if (lane == 0) {
      float inv = 1.f / s;
#pragma unroll
      for (int d = 0; d < 12; ++d) out[(ib + r) * 12 + d] = ad[d] * inv;
    }
  }
}

// ---------- fused layernorms + sumsq + bf16 convert (shuffle reductions) ----------
__global__ __launch_bounds__(256) void k_lnx(const float* f, const float* g, const float* b,
                                             const float* p, const float* pg, const float* pb,
                                             float* x0, unsigned short* x0h, float* sqv,
                                             int* degA) {
  __shared__ float row[512];
  __shared__ float wrA[4], wrB[4], wrC[4];
  int i = blockIdx.x, t = threadIdx.x, lane = t & 63, w = t >> 6;
  if (t == 0) degA[i] = 0;
  float v1 = f[i * 500 + t];
  float v2 = (t < 244) ? f[i * 500 + 256 + t] : 0.f;
  float part = v1 + v2;
#pragma unroll
  for (int o = 32; o > 0; o >>= 1) part += __shfl_xor(part, o);
  if (lane == 0) wrA[w] = part;
  __syncthreads();
  float m = (wrA[0] + wrA[1] + wrA[2] + wrA[3]) * (1.f / 500.f);
  float d1 = v1 - m, d2 = v2 - m;
  float pvv = d1 * d1 + ((t < 244) ? d2 * d2 : 0.f);
#pragma unroll
  for (int o = 32; o > 0; o >>= 1) pvv += __shfl_xor(pvv, o);
  if (lane == 0) wrB[w] = pvv;
  __syncthreads();
  float scale = 1.f / sqrtf((wrB[0] + wrB[1] + wrB[2] + wrB[3]) * (1.f / 500.f) + 1e-5f);
  row[t] = d1 * scale * g[t] + b[t];
  if (t < 244) row[256 + t] = d2 * scale * g[256 + t] + b[256 + t];
  if (t >= 244) {  // threads 244..255 handle the 12-wide pos layernorm
    int tt = t - 244;
    float pv[12], pm = 0.f;
#pragma unroll
    for (int d = 0; d < 12; ++d) { pv[d] = p[i * 12 + d]; pm += pv[d]; }
    pm *= (1.f / 12.f);
    float pvar = 0.f;
#pragma unroll
    for (int d = 0; d < 12; ++d) { float dd = pv[d] - pm; pvar += dd * dd; }
    pvar *= (1.f / 12.f);
    float ps = 1.f / sqrtf(pvar + 1e-5f);
    row[500 + tt] = (pv[tt] - pm) * ps * pg[tt] + pb[tt];
  }
  __syncthreads();
  float a = row[t], c = row[256 + t];
  float sq = a * a + c * c;
#pragma unroll
  for (int o = 32; o > 0; o >>= 1) sq += __shfl_xor(sq, o);
  if (lane == 0) wrC[w] = sq;
  __syncthreads();
  if (t == 0) sqv[i] = wrC[0] + wrC[1] + wrC[2] + wrC[3];
  x0[(size_t)i * 512 + t] = a;
  x0[(size_t)i * 512 + 256 + t] = c;
  x0h[(size_t)i * 512 + t] = f2bf(a);
  x0h[(size_t)i * 512 + 256 + t] = f2bf(c);
}

// ---------- MFMA d2 tiles (128x128, upper tile pairs): max / mask pass ----------
// T4 pipeline (m201 pattern): double-buffered LDS; issue next panel's 8 DMAs, then
// COUNTED s_waitcnt vmcnt(8), sched_barrier(0), raw s_barrier. No vmcnt(0) drain.
// Source pre-swizzled (chunk = (lane&7)^(row&7)); reads apply the same XOR.
// Pass A records per-tile min over gi<gj; pass B skips GEMM when tileMin >= thr,
// zeroes mirror tiles, and atomically accumulates integer deg[j].
#define BK 64
template <bool MASK>
__global__ __launch_bounds__(256) void k_d2m(const unsigned short* X, const float* sqv,
                                             unsigned* dmax, float* tileMin,
                                             unsigned char* ATm, int* deg) {
  __shared__ unsigned short As[2][128 * BK];
  __shared__ unsigned short Bs[2][128 * BK];
  __shared__ float wmax[4], wmin[4];
  const int NT = NN / 128;
  int bid0 = blockIdx.x;
  int bid = (bid0 & 7) * 66 + (bid0 >> 3);  // 528 total, bijective
  int ti = 0, rem = bid;
  while (rem >= NT - ti) { rem -= NT - ti; ++ti; }
  int tj = ti + rem;
  int t = threadIdx.x, lane = t & 63, w = t >> 6;
  int wr = w >> 1, wc = w & 1;  // wave's 64x64 sub-tile
  const unsigned short* Abase = X + (size_t)ti * 128 * 512;
  const unsigned short* Bbase = X + (size_t)tj * 128 * 512;
  int lr = lane >> 3, lc = lane & 7;

  float thr = 0.f;
  if (MASK) {
    thr = 0.5f * decf(*dmax);
    uint4 z = make_uint4(0u, 0u, 0u, 0u);
    if (ti != tj) {  // mirror tile (rows ti, cols tj) never receives mask writes
#pragma unroll
      for (int q0 = 0; q0 < 4; ++q0) {
        int q = t + q0 * 256; int r = q >> 3, c4 = q & 7;
        *(uint4*)(ATm + (size_t)(ti * 128 + r) * NN + tj * 128 + c4 * 16) = z;
      }
    }
    if (tileMin[blockIdx.x] >= thr) {  // no element can pass -> zero tile, skip GEMM
#pragma unroll
      for (int q0 = 0; q0 < 4; ++q0) {
        int q = t + q0 * 256; int r = q >> 3, c4 = q & 7;
        *(uint4*)(ATm + (size_t)(tj * 128 + r) * NN + ti * 128 + c4 * 16) = z;
      }
      return;
    }
  }

  auto stage = [&](int buf, int k0) {  // 8 DMAs per wave (4x A + 4x B)
#pragma unroll
    for (int i = 0; i < 4; ++i) {
      int q = w * 4 + i;
      int r = q * 8 + lr;
      int cs = lc ^ (r & 7);  // pre-swizzled source chunk
      __builtin_amdgcn_global_load_lds(
          (const __attribute__((address_space(1))) unsigned int*)(Abase + (size_t)r * 512 + k0 + cs * 8),
          (__attribute__((address_space(3))) unsigned int*)(&As[buf][q * 512]), 16, 0, 0);
      __builtin_amdgcn_global_load_lds(
          (const __attribute__((address_space(1))) unsigned int*)(Bbase + (size_t)r * 512 + k0 + cs * 8),
          (__attribute__((address_space(3))) unsigned int*)(&Bs[buf][q * 512]), 16, 0, 0);
    }
  };

  stage(0, 0);  // 8 outstanding

  f32x4 acc[4][4] = {};
  int rl = lane & 15, kg = lane >> 4;
  for (int step = 0; step < 8; ++step) {
    int cur = step & 1;
    if (step < 7) {
      stage(cur ^ 1, (step + 1) * BK);  // +8 in flight (16 total)
      asm volatile("s_waitcnt vmcnt(8)" ::: "memory");  // cur's 8 retired (in-order)
    } else {
      asm volatile("s_waitcnt vmcnt(0)" ::: "memory");
    }
    __builtin_amdgcn_sched_barrier(0);
    __builtin_amdgcn_s_barrier();  // all waves' cur panel visible
#pragma unroll
    for (int ks = 0; ks < 2; ++ks) {
      bf16x8 af[4], bq[4];
#pragma unroll
      for (int f = 0; f < 4; ++f) {
        int rA = wr * 64 + f * 16 + rl;
        af[f] = *(const bf16x8*)(&As[cur][rA * BK + (((ks * 4 + kg) ^ (rA & 7)) << 3)]);
        int rB = wc * 64 + f * 16 + rl;
        bq[f] = *(const bf16x8*)(&Bs[cur][rB * BK + (((ks * 4 + kg) ^ (rB & 7)) << 3)]);
      }
#pragma unroll
      for (int a = 0; a < 4; ++a)
#pragma unroll
        for (int b = 0; b < 4; ++b)
          acc[a][b] = __builtin_amdgcn_mfma_f32_16x16x32_bf16(af[a], bq[b], acc[a][b], 0, 0, 0);
    }
    __builtin_amdgcn_sched_barrier(0);  // pin ds_reads before the reuse barrier
    __builtin_amdgcn_s_barrier();       // all reads of cur done before its overwrite
  }
  // C/D layout: col = lane&15, row = (lane>>4)*4 + reg   [m89/m91 verified]
  int rbase = ti * 128 + wr * 64 + ((lane >> 4) << 2);
  int cbase = tj * 128 + wc * 64 + (lane & 15);
  if (!MASK) {
    float lm = -1e30f, lmin = 1e30f;
#pragma unroll
    for (int a = 0; a < 4; ++a) {
      float si[4];
#pragma unroll
      for (int r = 0; r < 4; ++r) si[r] = sqv[rbase + a * 16 + r];
#pragma unroll
      for (int b = 0; b < 4; ++b) {
        int gj = cbase + b * 16;
        float sj = sqv[gj];
#pragma unroll
        for (int r = 0; r < 4; ++r) {
          float d2v = si[r] - 2.f * acc[a][b][r] + sj;
          lm = fmaxf(lm, d2v);
          if (rbase + a * 16 + r < gj) lmin = fminf(lmin, d2v);
        }
      }
    }
#pragma unroll
    for (int o = 32; o > 0; o >>= 1) {
      lm = fmaxf(lm, __shfl_xor(lm, o));
      lmin = fminf(lmin, __shfl_xor(lmin, o));
    }
    if (lane == 0) { wmax[w] = lm; wmin[w] = lmin; }
    __syncthreads();
    if (t == 0) {
      atomicMax(dmax, encf(fmaxf(fmaxf(wmax[0], wmax[1]), fmaxf(wmax[2], wmax[3]))));
      tileMin[blockIdx.x] = fminf(fminf(wmin[0], wmin[1]), fminf(wmin[2], wmin[3]));
    }
  } else {
#pragma unroll
    for (int b = 0; b < 4; ++b) {
      int gj = cbase + b * 16;
      float sj = sqv[gj];
      int rowcnt = 0;
#pragma unroll
      for (int a = 0; a < 4; ++a) {
        int gi0 = rbase + a * 16;
        union { unsigned char c[4]; unsigned u; } m4;
#pragma unroll
        for (int r = 0; r < 4; ++r) {
          float d2v = sqv[gi0 + r] - 2.f * acc[a][b][r] + sj;
          unsigned char mv = (d2v < thr && (gi0 + r) < gj) ? 1 : 0;
          m4.c[r] = mv; rowcnt += mv;
        }
        *(unsigned*)(ATm + (size_t)gj * NN + gi0) = m4.u;  // AT[j][i..i+3]
      }
      if (rowcnt) atomicAdd(&deg[gj], rowcnt);
    }
  }
}

// ---------- fp32 GEMM + row scale: C[i][c] = (A@B)[i][c] / sqrt(1+deg[i]) ----------
// A-panel stored TRANSPOSED in LDS (Ast[kk][row]) -> av is one ds_read_b64 and
// bv one ds_read_b128: 2 LDS instrs per 8 FMAs (was 6 scalar reads). Same kk
// order and products -> bit-identical C.
__global__ __launch_bounds__(256) void k_gemm(const float* A, const float* B, const int* deg,
                                              float* C, int M, int N, int K) {
  __shared__ float Ast[16][34];
  __shared__ float Bs[16][64];
  int t = threadIdx.x, tx = t & 15, ty = t >> 4;
  int nbx = N >> 6;
  int total = gridDim.x;
  int bid0 = blockIdx.x;
  int bid = (bid0 & 7) * (total >> 3) + (bid0 >> 3);  // bijective: total%8==0
  int m0 = (bid / nbx) * 32, n0 = (bid % nbx) * 64;
  int ar = t >> 3, ac = (t * 2) & 15;   // A stage: 2 floats/thread (transposed write)
  int br = t >> 4, bc = (t & 15) * 4;   // B stage: 4 floats/thread
  float2 ra = *(const float2*)(A + (size_t)(m0 + ar) * K + ac);
  float4 rb = *(const float4*)(B + (size_t)br * N + n0 + bc);
  float acc[2][4] = {};
  for (int k0 = 0; k0 < K; k0 += 16) {
    Ast[ac][ar] = ra.x; Ast[ac + 1][ar] = ra.y;
    *(float4*)(&Bs[br][bc]) = rb;
    __syncthreads();
    if (k0 + 16 < K) {  // prefetch next panel (overlaps compute)
      ra = *(const float2*)(A + (size_t)(m0 + ar) * K + k0 + 16 + ac);
      rb = *(const float4*)(B + (size_t)(k0 + 16 + br) * N + n0 + bc);
    }
#pragma unroll
    for (int kk = 0; kk < 16; ++kk) {
      float2 av = *(const float2*)(&Ast[kk][ty * 2]);
      float4 bv = *(const float4*)(&Bs[kk][tx * 4]);
      acc[0][0] = fmaf(av.x, bv.x, acc[0][0]);
      acc[0][1] = fmaf(av.x, bv.y, acc[0][1]);
      acc[0][2] = fmaf(av.x, bv.z, acc[0][2]);
      acc[0][3] = fmaf(av.x, bv.w, acc[0][3]);
      acc[1][0] = fmaf(av.y, bv.x, acc[1][0]);
      acc[1][1] = fmaf(av.y, bv.y, acc[1][1]);
      acc[1][2] = fmaf(av.y, bv.z, acc[1][2]);
      acc[1][3] = fmaf(av.y, bv.w, acc[1][3]);
    }
    __syncthreads();
  }
#pragma unroll
  for (int a = 0; a < 2; ++a) {
    float dv = 1.f / sqrtf((float)(1 + deg[m0 + ty * 2 + a]));
#pragma unroll
    for (int b2 = 0; b2 < 4; ++b2)
      C[(size_t)(m0 + ty * 2 + a) * N + n0 + tx * 4 + b2] = acc[a][b2] * dv;
  }
}

// ---------- fused: xg row + relu + y2[j] = dinv[j]*dot(xg[j], Wpool) ----------
// Fast path: deg[j]==0 -> skip the mask scan (exact). y2 dot via shuffle reduce.
__global__ __launch_bounds__(256) void k_agg(const float* y, const unsigned char* ATm,
                                             const int* deg, const float* bias,
                                             const float* Wpool, float* out, float* y2, int n) {
  __shared__ unsigned char mrow[256];
  __shared__ int s_any;
  __shared__ float wred[4];
  int j = blockIdx.x, t = threadIdx.x, lane = t & 63, w = t >> 6;
  int dg = deg[j];
  float dj = 1.f / sqrtf((float)(1 + dg));
  float acc = y[(size_t)j * 256 + t];
  if (dg != 0) {
    for (int i0 = 0; i0 < n; i0 += 256) {
      if (t == 0) s_any = 0;
      __syncthreads();
      unsigned char m = ATm[(size_t)j * n + i0 + t];
      mrow[t] = m;
      if (m) s_any = 1;
      __syncthreads();
      if (s_any) {
        for (int u = 0; u < 256; ++u)
          if (mrow[u]) acc += y[(size_t)(i0 + u) * 256 + t];
      }
      __syncthreads();
    }
  }
  float o = fmaxf(dj * acc + bias[t], 0.f);
  out[(size_t)j * 256 + t] = o;
  float rv = o * Wpool[t];
#pragma unroll
  for (int os = 32; os > 0; os >>= 1) rv += __shfl_xor(rv, os);
  if (lane == 0) wred[w] = rv;
  __syncthreads();
  if (t == 0) y2[j] = dj * (wred[0] + wred[1] + wred[2] + wred[3]);
}

// ---------- score[j] = tanh(dinv[j]*(y2[j] + sum_{i:AT[j,i]} y2[i]) + bpool) ----------
__global__ __launch_bounds__(256) void k_scorek(const float* y2, const unsigned char* ATm,
                                                const int* deg, const float* bp,
                                                float* score, int n) {
  int w = threadIdx.x >> 6, lane = threadIdx.x & 63;
  int j = blockIdx.x * 4 + w;
  if (j >= n) return;
  int dg = deg[j];
  float dj = 1.f / sqrtf((float)(1 + dg));
  float s = 0.f;
  if (dg != 0) {  // deg>0: scan the row
    const uint4* row = (const uint4*)(ATm + (size_t)j * n);
    for (int p = lane; p < n / 16; p += 64) {
      uint4 v = row[p];
      if (v.x | v.y | v.z | v.w) {
        int base = p * 16;
#pragma unroll
        for (int q = 0; q < 4; ++q) {
          unsigned u = (&v.x)[q];
#pragma unroll
          for (int b2 = 0; b2 < 4; ++b2)
            if ((u >> (8 * b2)) & 0xffu) s += y2[base + q * 4 + b2];
        }
      }
    }
    for (int sh = 32; sh > 0; sh >>= 1) s += __shfl_down(s, sh);
  }
  if (lane == 0) score[j] = tanhf(dj * (y2[j] + s) + bp[0]);
}

// ---------- radix-select top-k (exact PyG set semantics; output in index order) ----------
__global__ __launch_bounds__(1024) void k_topsel(const float* score, int n, int k,
                                                 int* perm, float* vals) {
  __shared__ unsigned keys[4096];
  __shared__ unsigned hist[256];
  __shared__ unsigned s_state[2];  // [0]=prefix(cutoff), [1]=need(ties to take)
  __shared__ unsigned woff[16];
  int t = threadIdx.x, lane = t & 63, w = t >> 6;
  for (int i = t; i < 4096; i += 1024) keys[i] = (i < n) ? encf(score[i]) : 0u;
  if (t == 0) { s_state[0] = 0u; s_state[1] = (unsigned)k; }
  __syncthreads();

  for (int pass = 0; pass < 4; ++pass) {
    int shift = 24 - pass * 8;
    if (t < 256) hist[t] = 0u;
    __syncthreads();
    unsigned prefix = s_state[0];
    unsigned need = s_state[1];
    unsigned pmask = pass ? (0xFFFFFFFFu << (shift + 8)) : 0u;
    for (int i = t; i < n; i += 1024) {
      unsigned kk = keys[i];
      if ((kk & pmask) == prefix) atomicAdd(&hist[(kk >> shift) & 255u], 1u);
    }
    __syncthreads();
    if (w == 0) {
      unsigned h[4], suf[4];
#pragma unroll
      for (int r = 0; r < 4; ++r) h[r] = hist[lane * 4 + r];
      suf[3] = h[3]; suf[2] = h[2] + suf[3]; suf[1] = h[1] + suf[2]; suf[0] = h[0] + suf[1];
      unsigned lsum = suf[0];
      unsigned s = lsum;
#pragma unroll
      for (int off = 1; off < 64; off <<= 1) {
        unsigned o = __shfl_down(s, off);
        if (lane + off < 64) s += o;
      }
      unsigned Hl = s - lsum;
      int cand = -1; unsigned cumAt = 0, histAt = 0;
#pragma unroll
      for (int r = 0; r < 4; ++r) {
        unsigned c = Hl + suf[r];
        if (c >= need) { cand = lane * 4 + r; cumAt = c; histAt = h[r]; }
      }
      int gmax = cand;
#pragma unroll
      for (int off = 32; off > 0; off >>= 1) {
        int o = __shfl_xor(gmax, off);
        gmax = o > gmax ? o : gmax;
      }
      if (cand == gmax && cand >= 0) {
        s_state[0] = prefix | ((unsigned)cand << shift);
        s_state[1] = need - (cumAt - histAt);
      }
    }
    __syncthreads();
  }
  unsigned cutoff = s_state[0];
  unsigned tcount = s_state[1];
  unsigned G = (unsigned)k - tcount;

  int i0 = t * 4;
  unsigned loc[4], cnt = 0;
#pragma unroll
  for (int r = 0; r < 4; ++r) {
    unsigned kk = keys[i0 + r];
    unsigned g = (kk > cutoff) ? 1u : 0u;
    unsigned e = (kk == cutoff) ? 1u : 0u;
    loc[r] = cnt;
    cnt += (g << 16) | e;
  }
  unsigned inc = cnt;
#pragma unroll
  for (int off = 1; off < 64; off <<= 1) {
    unsigned o = __shfl_up(inc, off);
    if (lane >= off) inc += o;
  }
  if (lane == 63) woff[w] = inc;
  __syncthreads();
  if (t == 0) {
    unsigned run = 0;
    for (int q = 0; q < 16; ++q) { unsigned v = woff[q]; woff[q] = run; run += v; }
  }
  __syncthreads();
  unsigned base = woff[w] + (inc - cnt);
#pragma unroll
  for (int r = 0; r < 4; ++r) {
    unsigned kk = keys[i0 + r];
    unsigned p = base + loc[r];
    if (kk > cutoff) {
      unsigned pos = p >> 16;
      perm[pos] = i0 + r; vals[pos] = decf(kk);
    } else if (kk == cutoff) {
      unsigned pe = p & 0xffffu;
      if (pe < tcount) { perm[G + pe] = i0 + r; vals[G + pe] = decf(kk); }
    }
  }
}

// ---------- fused gather + readout partials ----------
__global__ __launch_bounds__(256) void k_gxp(const float* xg, const int* perm, const float* vals,
                                             float* xp, float* pmax, float* psum, int k) {
  int b = blockIdx.x, t = threadIdx.x;
  float m = -1e30f, s = 0.f;
  for (int r = b; r < k; r += RB) {
    float v = xg[(size_t)perm[r] * 256 + t] * vals[r];
    xp[(size_t)r * 256 + t] = v;
    m = fmaxf(m, v); s += v;
  }
  pmax[b * 256 + t] = m; psum[b * 256 + t] = s;
}
__global__ void k_rfin(const float* pmax, const float* psum, float* out, int k) {
  int t = threadIdx.x;
  float m = -1e30f, s = 0.f;
  for (int q = 0; q < RB; ++q) { m = fmaxf(m, pmax[q * 256 + t]); s += psum[q * 256 + t]; }
  out[t] += m;
  out[256 + t] += s / (float)k;
}

// ---------- ATnew[c][r] = ATold[perm[c]][perm[r]]  + deg for next layer ----------
// Fast path: degCur[sperm[c]]==0 -> source row all-zero -> vectorized zero writes.
__global__ __launch_bounds__(256) void k_gatherA(const unsigned char* ATold, const int* perm,
                                                 const int* degCur,
                                                 unsigned char* ATnew, int* degNext,
                                                 int nold, int kn) {
  __shared__ int sperm[4096];
  __shared__ int redi[256];
  int t = threadIdx.x, c = blockIdx.x;
  for (int r = t; r < kn; r += 256) sperm[r] = perm[r];
  __syncthreads();
  int src = sperm[c];
  unsigned char* orow = ATnew + (size_t)c * kn;
  if (degCur[src] == 0) {  // empty source row (kn % 16 == 0)
    uint4 z = make_uint4(0u, 0u, 0u, 0u);
    for (int r = t; r < kn / 16; r += 256) ((uint4*)orow)[r] = z;
    if (t == 0) degNext[c] = 0;
    return;
  }
  const unsigned char* row = ATold + (size_t)src * nold;
  int cnt = 0;
  for (int r = t; r < kn; r += 256) { unsigned char v = row[sperm[r]]; orow[r] = v; cnt += v; }
  redi[t] = cnt; __syncthreads();
  for (int s = 128; s > 0; s >>= 1) { if (t < s) redi[t] += redi[t + s]; __syncthreads(); }
  if (t == 0) degNext[c] = redi[0];
}

// ---------- host-side layer driver ----------
static void run_layer(hipStream_t stream, const float* x_in, int n, int inC,
                      const float* W, const float* b, const float* Wpool, const float* bpool,
                      int k, const unsigned char* ATcur, unsigned char* ATnext,
                      const int* degCur, int* degNext,
                      float* ybuf, float* xg, float* xp, float* y2,
                      float* score, int* perm, float* vals, float* pmax, float* psum, float* out) {
  k_gemm<<<(n / 32) * 4, 256, 0, stream>>>(x_in, W, degCur, ybuf, n, 256, inC);
  k_agg<<<n, 256, 0, stream>>>(ybuf, ATcur, degCur, b, Wpool, xg, y2, n);
  k_scorek<<<n / 4, 256, 0, stream>>>(y2, ATcur, degCur, bpool, score, n);
  k_topsel<<<1, 1024, 0, stream>>>(score, n, k, perm, vals);
  k_gxp<<<RB, 256, 0, stream>>>(xg, perm, vals, xp, pmax, psum, k);
  k_rfin<<<1, 256, 0, stream>>>(pmax, psum, out, k);
  if (ATnext) k_gatherA<<<k, 256, 0, stream>>>(ATcur, perm, degCur, ATnext, degNext, n, k);
}

extern "C" void kernel_launch(void* const* d_in, const int* in_sizes, int n_in,
                              void* d_out, int out_size, void* d_ws, size_t ws_size,
                              hipStream_t stream) {
  const float* feature = (const float*)d_in[0];
  const float* img     = (const float*)d_in[1];
  const float* Wp      = (const float*)d_in[2];
  const float* bp      = (const float*)d_in[3];
  const float* ln_f_g  = (const float*)d_in[4];
  const float* ln_f_b  = (const float*)d_in[5];
  const float* ln_p_g  = (const float*)d_in[6];
  const float* ln_p_b  = (const float*)d_in[7];
  const float* W1 = (const float*)d_in[8];   const float* b1 = (const float*)d_in[9];
  const float* Wpool1 = (const float*)d_in[10]; const float* bpool1 = (const float*)d_in[11];
  const float* W2 = (const float*)d_in[12];  const float* b2 = (const float*)d_in[13];
  const float* Wpool2 = (const float*)d_in[14]; const float* bpool2 = (const float*)d_in[15];
  const float* W3 = (const float*)d_in[16];  const float* b3 = (const float*)d_in[17];
  const float* Wpool3 = (const float*)d_in[18]; const float* bpool3 = (const float*)d_in[19];
  float* out = (float*)d_out;
  (void)in_sizes; (void)n_in; (void)out_size; (void)ws_size;

  char* w = (char*)d_ws;
  size_t off = 0;
  auto alloc = [&](size_t bytes) -> char* {
    off = (off + 255) & ~(size_t)255;
    char* p = w + off;
    off += bytes;
    return p;
  };
  float* pos0 = (float*)alloc((size_t)NN * 12 * 4);
  float* pos1 = (float*)alloc((size_t)NN * 12 * 4);
  float* x0   = (float*)alloc((size_t)NN * 512 * 4);
  unsigned short* x0h = (unsigned short*)alloc((size_t)NN * 512 * 2);
  float* sqv  = (float*)alloc((size_t)NN * 4);
  unsigned* dmax = (unsigned*)alloc(4);
  float* tileMin = (float*)alloc(528 * 4);
  int* degA = (int*)alloc((size_t)NN * 4);
  int* degB = (int*)alloc((size_t)NN * 4);
  float* ybuf = (float*)alloc((size_t)NN * 256 * 4);
  float* xg   = (float*)alloc((size_t)NN * 256 * 4);
  float* xp   = (float*)alloc((size_t)NN * 256 * 4);
  float* y2   = (float*)alloc((size_t)NN * 4);
  float* score= (float*)alloc((size_t)NN * 4);
  int*   perm = (int*)alloc((size_t)NN * 4);
  float* vals = (float*)alloc((size_t)NN * 4);
  float* pmax = (float*)alloc(RB * 256 * 4);
  float* psum = (float*)alloc(RB * 256 * 4);
  unsigned char* ATa = (unsigned char*)alloc((size_t)NN * NN);
  unsigned char* ATb = (unsigned char*)alloc((size_t)3072 * 3072);

  // preamble (init fused into k_pos; lnx zeroes degA)
  k_pos<<<(NN * 12 + 255) / 256, 256, 0, stream>>>(img, Wp, bp, pos0, out, dmax);
  k_attn3<<<NN / 8, 256, 0, stream>>>(pos0, pos1);
  k_lnx<<<NN, 256, 0, stream>>>(feature, ln_f_g, ln_f_b, pos1, ln_p_g, ln_p_b,
                                x0, x0h, sqv, degA);

  // edge construction via MFMA: max+tileMin pass, then pruned mask pass (+deg atomics)
  const int NT = NN / 128, TT = NT * (NT + 1) / 2;  // 32, 528
  k_d2m<false><<<TT, 256, 0, stream>>>(x0h, sqv, dmax, tileMin, nullptr, nullptr);
  k_d2m<true><<<TT, 256, 0, stream>>>(x0h, sqv, dmax, tileMin, ATa, degA);

  // three GCN + SAGPool + readout layers
  run_layer(stream, x0, 4096, 512, W1, b1, Wpool1, bpool1, 3072, ATa, ATb, degA, degB,
            ybuf, xg, xp, y2, score, perm, vals, pmax, psum, out);
  run_layer(stream, xp, 3072, 256, W2, b2, Wpool2, bpool2, 2304, ATb, ATa, degB, degA,
            ybuf, xg, xp, y2, score, perm, vals, pmax, psum, out);
  run_layer(stream, xp, 2304, 256, W3, b3, Wpool3, bpool3, 1728, ATa, nullptr, degA, nullptr,
            ybuf, xg, xp, y2, score, perm, vals, pmax, psum, out);
}

// Round 17
// 217.357 us; speedup vs baseline: 1.1849x; 1.0670x over previous
//
#include <hip/hip_runtime.h>
#include <math.h>

#define NN 4096
#define RB 128  // readout stage-1 blocks

typedef __attribute__((ext_vector_type(8))) short bf16x8;
typedef __attribute__((ext_vector_type(4))) float f32x4;

// ---------- helpers ----------
__device__ __forceinline__ unsigned encf(float f) {
  unsigned u = __float_as_uint(f);
  return (u & 0x80000000u) ? ~u : (u | 0x80000000u);
}
__device__ __forceinline__ float decf(unsigned u) {
  return __uint_as_float((u & 0x80000000u) ? (u ^ 0x80000000u) : ~u);
}
__device__ __forceinline__ unsigned short f2bf(float f) {
  unsigned u = __float_as_uint(f);
  return (unsigned short)((u + 0x7fffu + ((u >> 16) & 1u)) >> 16);
}

// ---------- pos = img @ Wp + bp  (+ init dmax in block 0) ----------
__global__ void k_pos(const float* img, const float* Wp, const float* bp, float* pos,
                      unsigned* dmax) {
  if (blockIdx.x == 0 && threadIdx.x == 0) *dmax = 0u;
  int t = blockIdx.x * 256 + threadIdx.x;
  if (t >= NN * 12) return;
  int i = t / 12, d = t % 12;
  float s = bp[d];
#pragma unroll
  for (int k = 0; k < 6; ++k) s += img[i * 6 + k] * Wp[k * 12 + d];
  pos[t] = s;
}

// ---------- attention, d=12, LDS-tiled keys, branch-free softmax ----------
__global__ __launch_bounds__(256) void k_attn3(const float* pos, float* out) {
  __shared__ float sp[12][256];
  int t = threadIdx.x, lane = t & 63, w = t >> 6;
  int ib = blockIdx.x * 8 + w * 2;  // 2 rows per wave, 8 per block
  float pi[2][12];
#pragma unroll
  for (int r = 0; r < 2; ++r)
#pragma unroll
    for (int d = 0; d < 12; ++d) pi[r][d] = pos[(ib + r) * 12 + d] * 0.28867513459481287f;
  float sl[2] = {0.f, 0.f};
  float acc[2][12] = {};
  const float4* p4 = (const float4*)pos;
  for (int kt = 0; kt < NN; kt += 256) {
    __syncthreads();  // previous tile fully consumed
    int j = kt + t;
    float4 a = p4[j * 3 + 0], b = p4[j * 3 + 1], c = p4[j * 3 + 2];
    sp[0][t] = a.x; sp[1][t] = a.y; sp[2][t] = a.z; sp[3][t] = a.w;
    sp[4][t] = b.x; sp[5][t] = b.y; sp[6][t] = b.z; sp[7][t] = b.w;
    sp[8][t] = c.x; sp[9][t] = c.y; sp[10][t] = c.z; sp[11][t] = c.w;
    __syncthreads();
#pragma unroll
    for (int q = 0; q < 4; ++q) {
      int jj = q * 64 + lane;
      float pj[12];
#pragma unroll
      for (int d = 0; d < 12; ++d) pj[d] = sp[d][jj];
#pragma unroll
      for (int r = 0; r < 2; ++r) {
        float s = 0.f;
#pragma unroll
        for (int d = 0; d < 12; ++d) s = fmaf(pi[r][d], pj[d], s);
        float e = __expf(s);
        sl[r] += e;
#pragma unroll
        for (int d = 0; d < 12; ++d) acc[r][d] = fmaf(e, pj[d], acc[r][d]);
      }
    }
  }
#pragma unroll
  for (int r = 0; r < 2; ++r) {
    float s = sl[r];
#pragma unroll
    for (int o = 32; o > 0; o >>= 1) s += __shfl_xor(s, o);
    float ad[12];
#pragma unroll
    for (int d = 0; d < 12; ++d) {
      ad[d] = acc[r][d];
#pragma unroll
      for (int o = 32; o > 0; o >>= 1) ad[d] += __shfl_xor(ad[d], o);
    }
    if (lane == 0) {
      float inv = 1.f / s;
#pragma unroll
      for (int d = 0; d < 12; ++d) out[(ib + r) * 12 + d] = ad[d] * inv;
    }
  }
}

// ---------- fused layernorms + sumsq + bf16 convert (shuffle reductions) ----------
__global__ __launch_bounds__(256) void k_lnx(const float* f, const float* g, const float* b,
                                             const float* p, const float* pg, const float* pb,
                                             float* x0, unsigned short* x0h, float* sqv,
                                             int* degA) {
  __shared__ float row[512];
  __shared__ float wrA[4], wrB[4], wrC[4];
  int i = blockIdx.x, t = threadIdx.x, lane = t & 63, w = t >> 6;
  if (t == 0) degA[i] = 0;
  float v1 = f[i * 500 + t];
  float v2 = (t < 244) ? f[i * 500 + 256 + t] : 0.f;
  float part = v1 + v2;
#pragma unroll
  for (int o = 32; o > 0; o >>= 1) part += __shfl_xor(part, o);
  if (lane == 0) wrA[w] = part;
  __syncthreads();
  float m = (wrA[0] + wrA[1] + wrA[2] + wrA[3]) * (1.f / 500.f);
  float d1 = v1 - m, d2 = v2 - m;
  float pvv = d1 * d1 + ((t < 244) ? d2 * d2 : 0.f);
#pragma unroll
  for (int o = 32; o > 0; o >>= 1) pvv += __shfl_xor(pvv, o);
  if (lane == 0) wrB[w] = pvv;
  __syncthreads();
  float scale = 1.f / sqrtf((wrB[0] + wrB[1] + wrB[2] + wrB[3]) * (1.f / 500.f) + 1e-5f);
  row[t] = d1 * scale * g[t] + b[t];
  if (t < 244) row[256 + t] = d2 * scale * g[256 + t] + b[256 + t];
  if (t >= 244) {  // threads 244..255 handle the 12-wide pos layernorm
    int tt = t - 244;
    float pv[12], pm = 0.f;
#pragma unroll
    for (int d = 0; d < 12; ++d) { pv[d] = p[i * 12 + d]; pm += pv[d]; }
    pm *= (1.f / 12.f);
    float pvar = 0.f;
#pragma unroll
    for (int d = 0; d < 12; ++d) { float dd = pv[d] - pm; pvar += dd * dd; }
    pvar *= (1.f / 12.f);
    float ps = 1.f / sqrtf(pvar + 1e-5f);
    row[500 + tt] = (pv[tt] - pm) * ps * pg[tt] + pb[tt];
  }
  __syncthreads();
  float a = row[t], c = row[256 + t];
  float sq = a * a + c * c;
#pragma unroll
  for (int o = 32; o > 0; o >>= 1) sq += __shfl_xor(sq, o);
  if (lane == 0) wrC[w] = sq;
  __syncthreads();
  if (t == 0) sqv[i] = wrC[0] + wrC[1] + wrC[2] + wrC[3];
  x0[(size_t)i * 512 + t] = a;
  x0[(size_t)i * 512 + 256 + t] = c;
  x0h[(size_t)i * 512 + t] = f2bf(a);
  x0h[(size_t)i * 512 + 256 + t] = f2bf(c);
}

// ---------- MFMA d2 tiles (128x128, upper tile pairs): max / mask pass ----------
// T4 pipeline: double-buffered LDS; issue next panel's 8 DMAs, COUNTED vmcnt(8),
// sched_barrier(0), raw s_barrier; T5 setprio(1) around the MFMA cluster.
// Source pre-swizzled (chunk = (lane&7)^(row&7)); reads apply the same XOR.
// Pass A records per-tile min over gi<gj; pass B skips GEMM when tileMin >= thr,
// zeroes mirror tiles, and atomically accumulates integer deg[j].
#define BK 64
template <bool MASK>
__global__ __launch_bounds__(256) void k_d2m(const unsigned short* X, const float* sqv,
                                             unsigned* dmax, float* tileMin,
                                             unsigned char* ATm, int* deg) {
  __shared__ unsigned short As[2][128 * BK];
  __shared__ unsigned short Bs[2][128 * BK];
  __shared__ float wmax[4], wmin[4];
  const int NT = NN / 128;
  int bid0 = blockIdx.x;
  int bid = (bid0 & 7) * 66 + (bid0 >> 3);  // 528 total, bijective
  int ti = 0, rem = bid;
  while (rem >= NT - ti) { rem -= NT - ti; ++ti; }
  int tj = ti + rem;
  int t = threadIdx.x, lane = t & 63, w = t >> 6;
  int wr = w >> 1, wc = w & 1;  // wave's 64x64 sub-tile
  const unsigned short* Abase = X + (size_t)ti * 128 * 512;
  const unsigned short* Bbase = X + (size_t)tj * 128 * 512;
  int lr = lane >> 3, lc = lane & 7;

  float thr = 0.f;
  if (MASK) {
    thr = 0.5f * decf(*dmax);
    uint4 z = make_uint4(0u, 0u, 0u, 0u);
    if (ti != tj) {  // mirror tile (rows ti, cols tj) never receives mask writes
#pragma unroll
      for (int q0 = 0; q0 < 4; ++q0) {
        int q = t + q0 * 256; int r = q >> 3, c4 = q & 7;
        *(uint4*)(ATm + (size_t)(ti * 128 + r) * NN + tj * 128 + c4 * 16) = z;
      }
    }
    if (tileMin[blockIdx.x] >= thr) {  // no element can pass -> zero tile, skip GEMM
#pragma unroll
      for (int q0 = 0; q0 < 4; ++q0) {
        int q = t + q0 * 256; int r = q >> 3, c4 = q & 7;
        *(uint4*)(ATm + (size_t)(tj * 128 + r) * NN + ti * 128 + c4 * 16) = z;
      }
      return;
    }
  }

  auto stage = [&](int buf, int k0) {  // 8 DMAs per wave (4x A + 4x B)
#pragma unroll
    for (int i = 0; i < 4; ++i) {
      int q = w * 4 + i;
      int r = q * 8 + lr;
      int cs = lc ^ (r & 7);  // pre-swizzled source chunk
      __builtin_amdgcn_global_load_lds(
          (const __attribute__((address_space(1))) unsigned int*)(Abase + (size_t)r * 512 + k0 + cs * 8),
          (__attribute__((address_space(3))) unsigned int*)(&As[buf][q * 512]), 16, 0, 0);
      __builtin_amdgcn_global_load_lds(
          (const __attribute__((address_space(1))) unsigned int*)(Bbase + (size_t)r * 512 + k0 + cs * 8),
          (__attribute__((address_space(3))) unsigned int*)(&Bs[buf][q * 512]), 16, 0, 0);
    }
  };

  stage(0, 0);  // 8 outstanding

  f32x4 acc[4][4] = {};
  int rl = lane & 15, kg = lane >> 4;
  for (int step = 0; step < 8; ++step) {
    int cur = step & 1;
    if (step < 7) {
      stage(cur ^ 1, (step + 1) * BK);  // +8 in flight (16 total)
      asm volatile("s_waitcnt vmcnt(8)" ::: "memory");  // cur's 8 retired (in-order)
    } else {
      asm volatile("s_waitcnt vmcnt(0)" ::: "memory");
    }
    __builtin_amdgcn_sched_barrier(0);
    __builtin_amdgcn_s_barrier();  // all waves' cur panel visible
    __builtin_amdgcn_s_setprio(1);
#pragma unroll
    for (int ks = 0; ks < 2; ++ks) {
      bf16x8 af[4], bq[4];
#pragma unroll
      for (int f = 0; f < 4; ++f) {
        int rA = wr * 64 + f * 16 + rl;
        af[f] = *(const bf16x8*)(&As[cur][rA * BK + (((ks * 4 + kg) ^ (rA & 7)) << 3)]);
        int rB = wc * 64 + f * 16 + rl;
        bq[f] = *(const bf16x8*)(&Bs[cur][rB * BK + (((ks * 4 + kg) ^ (rB & 7)) << 3)]);
      }
#pragma unroll
      for (int a = 0; a < 4; ++a)
#pragma unroll
        for (int b = 0; b < 4; ++b)
          acc[a][b] = __builtin_amdgcn_mfma_f32_16x16x32_bf16(af[a], bq[b], acc[a][b], 0, 0, 0);
    }
    __builtin_amdgcn_s_setprio(0);
    __builtin_amdgcn_sched_barrier(0);  // pin ds_reads before the reuse barrier
    __builtin_amdgcn_s_barrier();       // all reads of cur done before its overwrite
  }
  // C/D layout: col = lane&15, row = (lane>>4)*4 + reg   [m89/m91 verified]
  int rbase = ti * 128 + wr * 64 + ((lane >> 4) << 2);
  int cbase = tj * 128 + wc * 64 + (lane & 15);
  if (!MASK) {
    float lm = -1e30f, lmin = 1e30f;
#pragma unroll
    for (int a = 0; a < 4; ++a) {
      float si[4];
#pragma unroll
      for (int r = 0; r < 4; ++r) si[r] = sqv[rbase + a * 16 + r];
#pragma unroll
      for (int b = 0; b < 4; ++b) {
        int gj = cbase + b * 16;
        float sj = sqv[gj];
#pragma unroll
        for (int r = 0; r < 4; ++r) {
          float d2v = si[r] - 2.f * acc[a][b][r] + sj;
          lm = fmaxf(lm, d2v);
          if (rbase + a * 16 + r < gj) lmin = fminf(lmin, d2v);
        }
      }
    }
#pragma unroll
    for (int o = 32; o > 0; o >>= 1) {
      lm = fmaxf(lm, __shfl_xor(lm, o));
      lmin = fminf(lmin, __shfl_xor(lmin, o));
    }
    if (lane == 0) { wmax[w] = lm; wmin[w] = lmin; }
    __syncthreads();
    if (t == 0) {
      atomicMax(dmax, encf(fmaxf(fmaxf(wmax[0], wmax[1]), fmaxf(wmax[2], wmax[3]))));
      tileMin[blockIdx.x] = fminf(fminf(wmin[0], wmin[1]), fminf(wmin[2], wmin[3]));
    }
  } else {
#pragma unroll
    for (int b = 0; b < 4; ++b) {
      int gj = cbase + b * 16;
      float sj = sqv[gj];
      int rowcnt = 0;
#pragma unroll
      for (int a = 0; a < 4; ++a) {
        int gi0 = rbase + a * 16;
        union { unsigned char c[4]; unsigned u; } m4;
#pragma unroll
        for (int r = 0; r < 4; ++r) {
          float d2v = sqv[gi0 + r] - 2.f * acc[a][b][r] + sj;
          unsigned char mv = (d2v < thr && (gi0 + r) < gj) ? 1 : 0;
          m4.c[r] = mv; rowcnt += mv;
        }
        *(unsigned*)(ATm + (size_t)gj * NN + gi0) = m4.u;  // AT[j][i..i+3]
      }
      if (rowcnt) atomicAdd(&deg[gj], rowcnt);
    }
  }
}

// ---------- fp32 GEMM + row scale: C[i][c] = (A@B)[i][c] / sqrt(1+deg[i]) ----------
__global__ __launch_bounds__(256) void k_gemm(const float* A, const float* B, const int* deg,
                                              float* C, int M, int N, int K) {
  __shared__ float Ast[16][34];
  __shared__ float Bs[16][64];
  int t = threadIdx.x, tx = t & 15, ty = t >> 4;
  int nbx = N >> 6;
  int total = gridDim.x;
  int bid0 = blockIdx.x;
  int bid = (bid0 & 7) * (total >> 3) + (bid0 >> 3);  // bijective: total%8==0
  int m0 = (bid / nbx) * 32, n0 = (bid % nbx) * 64;
  int ar = t >> 3, ac = (t * 2) & 15;   // A stage: 2 floats/thread (transposed write)
  int br = t >> 4, bc = (t & 15) * 4;   // B stage: 4 floats/thread
  float2 ra = *(const float2*)(A + (size_t)(m0 + ar) * K + ac);
  float4 rb = *(const float4*)(B + (size_t)br * N + n0 + bc);
  float acc[2][4] = {};
  for (int k0 = 0; k0 < K; k0 += 16) {
    Ast[ac][ar] = ra.x; Ast[ac + 1][ar] = ra.y;
    *(float4*)(&Bs[br][bc]) = rb;
    __syncthreads();
    if (k0 + 16 < K) {  // prefetch next panel (overlaps compute)
      ra = *(const float2*)(A + (size_t)(m0 + ar) * K + k0 + 16 + ac);
      rb = *(const float4*)(B + (size_t)(k0 + 16 + br) * N + n0 + bc);
    }
#pragma unroll
    for (int kk = 0; kk < 16; ++kk) {
      float2 av = *(const float2*)(&Ast[kk][ty * 2]);
      float4 bv = *(const float4*)(&Bs[kk][tx * 4]);
      acc[0][0] = fmaf(av.x, bv.x, acc[0][0]);
      acc[0][1] = fmaf(av.x, bv.y, acc[0][1]);
      acc[0][2] = fmaf(av.x, bv.z, acc[0][2]);
      acc[0][3] = fmaf(av.x, bv.w, acc[0][3]);
      acc[1][0] = fmaf(av.y, bv.x, acc[1][0]);
      acc[1][1] = fmaf(av.y, bv.y, acc[1][1]);
      acc[1][2] = fmaf(av.y, bv.z, acc[1][2]);
      acc[1][3] = fmaf(av.y, bv.w, acc[1][3]);
    }
    __syncthreads();
  }
#pragma unroll
  for (int a = 0; a < 2; ++a) {
    float dv = 1.f / sqrtf((float)(1 + deg[m0 + ty * 2 + a]));
#pragma unroll
    for (int b2 = 0; b2 < 4; ++b2)
      C[(size_t)(m0 + ty * 2 + a) * N + n0 + tx * 4 + b2] = acc[a][b2] * dv;
  }
}

// ---------- fused: xg row + relu + y2[j] = dinv[j]*dot(xg[j], Wpool) ----------
__global__ __launch_bounds__(256) void k_agg(const float* y, const unsigned char* ATm,
                                             const int* deg, const float* bias,
                                             const float* Wpool, float* out, float* y2, int n) {
  __shared__ unsigned char mrow[256];
  __shared__ int s_any;
  __shared__ float wred[4];
  int j = blockIdx.x, t = threadIdx.x, lane = t & 63, w = t >> 6;
  int dg = deg[j];
  float dj = 1.f / sqrtf((float)(1 + dg));
  float acc = y[(size_t)j * 256 + t];
  if (dg != 0) {
    for (int i0 = 0; i0 < n; i0 += 256) {
      if (t == 0) s_any = 0;
      __syncthreads();
      unsigned char m = ATm[(size_t)j * n + i0 + t];
      mrow[t] = m;
      if (m) s_any = 1;
      __syncthreads();
      if (s_any) {
        for (int u = 0; u < 256; ++u)
          if (mrow[u]) acc += y[(size_t)(i0 + u) * 256 + t];
      }
      __syncthreads();
    }
  }
  float o = fmaxf(dj * acc + bias[t], 0.f);
  out[(size_t)j * 256 + t] = o;
  float rv = o * Wpool[t];
#pragma unroll
  for (int os = 32; os > 0; os >>= 1) rv += __shfl_xor(rv, os);
  if (lane == 0) wred[w] = rv;
  __syncthreads();
  if (t == 0) y2[j] = dj * (wred[0] + wred[1] + wred[2] + wred[3]);
}

// ---------- score[j] = tanh(dinv[j]*(y2[j] + sum_{i:AT[j,i]} y2[i]) + bpool) ----------
__global__ __launch_bounds__(256) void k_scorek(const float* y2, const unsigned char* ATm,
                                                const int* deg, const float* bp,
                                                float* score, int n) {
  int w = threadIdx.x >> 6, lane = threadIdx.x & 63;
  int j = blockIdx.x * 4 + w;
  if (j >= n) return;
  int dg = deg[j];
  float dj = 1.f / sqrtf((float)(1 + dg));
  float s = 0.f;
  if (dg != 0) {  // deg>0: scan the row
    const uint4* row = (const uint4*)(ATm + (size_t)j * n);
    for (int p = lane; p < n / 16; p += 64) {
      uint4 v = row[p];
      if (v.x | v.y | v.z | v.w) {
        int base = p * 16;
#pragma unroll
        for (int q = 0; q < 4; ++q) {
          unsigned u = (&v.x)[q];
#pragma unroll
          for (int b2 = 0; b2 < 4; ++b2)
            if ((u >> (8 * b2)) & 0xffu) s += y2[base + q * 4 + b2];
        }
      }
    }
    for (int sh = 32; sh > 0; sh >>= 1) s += __shfl_down(s, sh);
  }
  if (lane == 0) score[j] = tanhf(dj * (y2[j] + s) + bp[0]);
}

// ---------- radix-select top-k (exact PyG set semantics; output in index order) ----------
__global__ __launch_bounds__(1024) void k_topsel(const float* score, int n, int k,
                                                 int* perm, float* vals) {
  __shared__ unsigned keys[4096];
  __shared__ unsigned hist[256];
  __shared__ unsigned s_state[2];  // [0]=prefix(cutoff), [1]=need(ties to take)
  __shared__ unsigned woff[16];
  int t = threadIdx.x, lane = t & 63, w = t >> 6;
  for (int i = t; i < 4096; i += 1024) keys[i] = (i < n) ? encf(score[i]) : 0u;
  if (t == 0) { s_state[0] = 0u; s_state[1] = (unsigned)k; }
  __syncthreads();

  for (int pass = 0; pass < 4; ++pass) {
    int shift = 24 - pass * 8;
    if (t < 256) hist[t] = 0u;
    __syncthreads();
    unsigned prefix = s_state[0];
    unsigned need = s_state[1];
    unsigned pmask = pass ? (0xFFFFFFFFu << (shift + 8)) : 0u;
    for (int i = t; i < n; i += 1024) {
      unsigned kk = keys[i];
      if ((kk & pmask) == prefix) atomicAdd(&hist[(kk >> shift) & 255u], 1u);
    }
    __syncthreads();
    if (w == 0) {
      unsigned h[4], suf[4];
#pragma unroll
      for (int r = 0; r < 4; ++r) h[r] = hist[lane * 4 + r];
      suf[3] = h[3]; suf[2] = h[2] + suf[3]; suf[1] = h[1] + suf[2]; suf[0] = h[0] + suf[1];
      unsigned lsum = suf[0];
      unsigned s = lsum;
#pragma unroll
      for (int off = 1; off < 64; off <<= 1) {
        unsigned o = __shfl_down(s, off);
        if (lane + off < 64) s += o;
      }
      unsigned Hl = s - lsum;
      int cand = -1; unsigned cumAt = 0, histAt = 0;
#pragma unroll
      for (int r = 0; r < 4; ++r) {
        unsigned c = Hl + suf[r];
        if (c >= need) { cand = lane * 4 + r; cumAt = c; histAt = h[r]; }
      }
      int gmax = cand;
#pragma unroll
      for (int off = 32; off > 0; off >>= 1) {
        int o = __shfl_xor(gmax, off);
        gmax = o > gmax ? o : gmax;
      }
      if (cand == gmax && cand >= 0) {
        s_state[0] = prefix | ((unsigned)cand << shift);
        s_state[1] = need - (cumAt - histAt);
      }
    }
    __syncthreads();
  }
  unsigned cutoff = s_state[0];
  unsigned tcount = s_state[1];
  unsigned G = (unsigned)k - tcount;

  int i0 = t * 4;
  unsigned loc[4], cnt = 0;
#pragma unroll
  for (int r = 0; r < 4; ++r) {
    unsigned kk = keys[i0 + r];
    unsigned g = (kk > cutoff) ? 1u : 0u;
    unsigned e = (kk == cutoff) ? 1u : 0u;
    loc[r] = cnt;
    cnt += (g << 16) | e;
  }
  unsigned inc = cnt;
#pragma unroll
  for (int off = 1; off < 64; off <<= 1) {
    unsigned o = __shfl_up(inc, off);
    if (lane >= off) inc += o;
  }
  if (lane == 63) woff[w] = inc;
  __syncthreads();
  if (t == 0) {
    unsigned run = 0;
    for (int q = 0; q < 16; ++q) { unsigned v = woff[q]; woff[q] = run; run += v; }
  }
  __syncthreads();
  unsigned base = woff[w] + (inc - cnt);
#pragma unroll
  for (int r = 0; r < 4; ++r) {
    unsigned kk = keys[i0 + r];
    unsigned p = base + loc[r];
    if (kk > cutoff) {
      unsigned pos = p >> 16;
      perm[pos] = i0 + r; vals[pos] = decf(kk);
    } else if (kk == cutoff) {
      unsigned pe = p & 0xffffu;
      if (pe < tcount) { perm[G + pe] = i0 + r; vals[G + pe] = decf(kk); }
    }
  }
}

// ---------- merged pool: blocks [0,RB) gather+readout partials; [RB,RB+kn) gatherA ----------
__global__ __launch_bounds__(256) void k_pool(const float* xg, const int* perm, const float* vals,
                                              float* xp, float* pmax, float* psum, int k,
                                              const unsigned char* ATold, const int* degCur,
                                              unsigned char* ATnew, int* degNext, int nold) {
  __shared__ int sperm[4096];
  __shared__ int redi[256];
  int b = blockIdx.x, t = threadIdx.x;
  if (b < RB) {  // gather xp rows + per-block max/sum partials
    float m = -1e30f, s = 0.f;
    for (int r = b; r < k; r += RB) {
      float v = xg[(size_t)perm[r] * 256 + t] * vals[r];
      xp[(size_t)r * 256 + t] = v;
      m = fmaxf(m, v); s += v;
    }
    pmax[b * 256 + t] = m; psum[b * 256 + t] = s;
    return;
  }
  // gatherA: ATnew[c][r] = ATold[perm[c]][perm[r]], degNext[c] = row count
  int c = b - RB;
  for (int r = t; r < k; r += 256) sperm[r] = perm[r];
  __syncthreads();
  int src = sperm[c];
  unsigned char* orow = ATnew + (size_t)c * k;
  if (degCur[src] == 0) {  // empty source row (k % 16 == 0)
    uint4 z = make_uint4(0u, 0u, 0u, 0u);
    for (int r = t; r < k / 16; r += 256) ((uint4*)orow)[r] = z;
    if (t == 0) degNext[c] = 0;
    return;
  }
  const unsigned char* row = ATold + (size_t)src * nold;
  int cnt = 0;
  for (int r = t; r < k; r += 256) { unsigned char v = row[sperm[r]]; orow[r] = v; cnt += v; }
  redi[t] = cnt; __syncthreads();
  for (int s = 128; s > 0; s >>= 1) { if (t < s) redi[t] += redi[t + s]; __syncthreads(); }
  if (t == 0) degNext[c] = redi[0];
}

// ---------- single deferred readout finalize for all 3 layers ----------
__global__ void k_rfin3(const float* pm0, const float* ps0, int k0,
                        const float* pm1, const float* ps1, int k1,
                        const float* pm2, const float* ps2, int k2, float* out) {
  int t = threadIdx.x;
  float m0 = -1e30f, s0 = 0.f, m1 = -1e30f, s1 = 0.f, m2 = -1e30f, s2 = 0.f;
  for (int q = 0; q < RB; ++q) {
    m0 = fmaxf(m0, pm0[q * 256 + t]); s0 += ps0[q * 256 + t];
    m1 = fmaxf(m1, pm1[q * 256 + t]); s1 += ps1[q * 256 + t];
    m2 = fmaxf(m2, pm2[q * 256 + t]); s2 += ps2[q * 256 + t];
  }
  out[t] = m0 + m1 + m2;  // same left-assoc order as per-layer +=
  out[256 + t] = s0 / (float)k0 + s1 / (float)k1 + s2 / (float)k2;
}

// ---------- host-side layer driver ----------
static void run_layer(hipStream_t stream, const float* x_in, int n, int inC,
                      const float* W, const float* b, const float* Wpool, const float* bpool,
                      int k, const unsigned char* ATcur, unsigned char* ATnext,
                      const int* degCur, int* degNext,
                      float* ybuf, float* xg, float* xp, float* y2,
                      float* score, int* perm, float* vals, float* pmax, float* psum) {
  k_gemm<<<(n / 32) * 4, 256, 0, stream>>>(x_in, W, degCur, ybuf, n, 256, inC);
  k_agg<<<n, 256, 0, stream>>>(ybuf, ATcur, degCur, b, Wpool, xg, y2, n);
  k_scorek<<<n / 4, 256, 0, stream>>>(y2, ATcur, degCur, bpool, score, n);
  k_topsel<<<1, 1024, 0, stream>>>(score, n, k, perm, vals);
  int grid = RB + (ATnext ? k : 0);
  k_pool<<<grid, 256, 0, stream>>>(xg, perm, vals, xp, pmax, psum, k,
                                   ATcur, degCur, ATnext, degNext, n);
}

extern "C" void kernel_launch(void* const* d_in, const int* in_sizes, int n_in,
                              void* d_out, int out_size, void* d_ws, size_t ws_size,
                              hipStream_t stream) {
  const float* feature = (const float*)d_in[0];
  const float* img     = (const float*)d_in[1];
  const float* Wp      = (const float*)d_in[2];
  const float* bp      = (const float*)d_in[3];
  const float* ln_f_g  = (const float*)d_in[4];
  const float* ln_f_b  = (const float*)d_in[5];
  const float* ln_p_g  = (const float*)d_in[6];
  const float* ln_p_b  = (const float*)d_in[7];
  const float* W1 = (const float*)d_in[8];   const float* b1 = (const float*)d_in[9];
  const float* Wpool1 = (const float*)d_in[10]; const float* bpool1 = (const float*)d_in[11];
  const float* W2 = (const float*)d_in[12];  const float* b2 = (const float*)d_in[13];
  const float* Wpool2 = (const float*)d_in[14]; const float* bpool2 = (const float*)d_in[15];
  const float* W3 = (const float*)d_in[16];  const float* b3 = (const float*)d_in[17];
  const float* Wpool3 = (const float*)d_in[18]; const float* bpool3 = (const float*)d_in[19];
  float* out = (float*)d_out;
  (void)in_sizes; (void)n_in; (void)out_size; (void)ws_size;

  char* w = (char*)d_ws;
  size_t off = 0;
  auto alloc = [&](size_t bytes) -> char* {
    off = (off + 255) & ~(size_t)255;
    char* p = w + off;
    off += bytes;
    return p;
  };
  float* pos0 = (float*)alloc((size_t)NN * 12 * 4);
  float* pos1 = (float*)alloc((size_t)NN * 12 * 4);
  float* x0   = (float*)alloc((size_t)NN * 512 * 4);
  unsigned short* x0h = (unsigned short*)alloc((size_t)NN * 512 * 2);
  float* sqv  = (float*)alloc((size_t)NN * 4);
  unsigned* dmax = (unsigned*)alloc(4);
  float* tileMin = (float*)alloc(528 * 4);
  int* degA = (int*)alloc((size_t)NN * 4);
  int* degB = (int*)alloc((size_t)NN * 4);
  float* ybuf = (float*)alloc((size_t)NN * 256 * 4);
  float* xg   = (float*)alloc((size_t)NN * 256 * 4);
  float* xp   = (float*)alloc((size_t)NN * 256 * 4);
  float* y2   = (float*)alloc((size_t)NN * 4);
  float* score= (float*)alloc((size_t)NN * 4);
  int*   perm = (int*)alloc((size_t)NN * 4);
  float* vals = (float*)alloc((size_t)NN * 4);
  float* pmax0 = (float*)alloc(RB * 256 * 4);
  float* psum0 = (float*)alloc(RB * 256 * 4);
  float* pmax1 = (float*)alloc(RB * 256 * 4);
  float* psum1 = (float*)alloc(RB * 256 * 4);
  float* pmax2 = (float*)alloc(RB * 256 * 4);
  float* psum2 = (float*)alloc(RB * 256 * 4);
  unsigned char* ATa = (unsigned char*)alloc((size_t)NN * NN);
  unsigned char* ATb = (unsigned char*)alloc((size_t)3072 * 3072);

  // preamble (init fused into k_pos; lnx zeroes degA)
  k_pos<<<(NN * 12 + 255) / 256, 256, 0, stream>>>(img, Wp, bp, pos0, dmax);
  k_attn3<<<NN / 8, 256, 0, stream>>>(pos0, pos1);
  k_lnx<<<NN, 256, 0, stream>>>(feature, ln_f_g, ln_f_b, pos1, ln_p_g, ln_p_b,
                                x0, x0h, sqv, degA);

  // edge construction via MFMA: max+tileMin pass, then pruned mask pass (+deg atomics)
  const int NT = NN / 128, TT = NT * (NT + 1) / 2;  // 32, 528
  k_d2m<false><<<TT, 256, 0, stream>>>(x0h, sqv, dmax, tileMin, nullptr, nullptr);
  k_d2m<true><<<TT, 256, 0, stream>>>(x0h, sqv, dmax, tileMin, ATa, degA);

  // three GCN + SAGPool + readout layers (readout finalize deferred to k_rfin3)
  run_layer(stream, x0, 4096, 512, W1, b1, Wpool1, bpool1, 3072, ATa, ATb, degA, degB,
            ybuf, xg, xp, y2, score, perm, vals, pmax0, psum0);
  run_layer(stream, xp, 3072, 256, W2, b2, Wpool2, bpool2, 2304, ATb, ATa, degB, degA,
            ybuf, xg, xp, y2, score, perm, vals, pmax1, psum1);
  run_layer(stream, xp, 2304, 256, W3, b3, Wpool3, bpool3, 1728, ATa, nullptr, degA, nullptr,
            ybuf, xg, xp, y2, score, perm, vals, pmax2, psum2);
  k_rfin3<<<1, 256, 0, stream>>>(pmax0, psum0, 3072, pmax1, psum1, 2304,
                                 pmax2, psum2, 1728, out);
}